// Round 5
// baseline (1499.038 us; speedup 1.0000x reference)
//
#include <hip/hip_runtime.h>
#include <math.h>

#define PI_F 3.14159265358979323846f

#define NS   4
#define CIN  64
#define HH   128
#define WW   128
#define KXN  65          // rfft last-axis size
#define NPIX (HH*WW)
#define MMAT 1600        // CIN*5*5
#define NIT  12          // CG iterations

// float offsets in workspace (~6.8 MB)
#define OFF_SINV 0
#define OFF_E    33280
#define OFF_ER   98816
#define OFF_EW   165376
#define OFF_VR   231936
#define OFF_WB   298496
#define OFF_R    364032      // 4*64*64*81 = 1,327,104 floats
#define OFF_PM   1691136    // 6400 floats
// CG state reuses the (dead-by-then) front-end scratch at offset 0:
#define OFF_DV   0
#define OFF_RV   6400
#define OFF_PV   12800
#define OFF_AP   19200
#define OFF_SC   25600      // per-sample 64 slots: rr at [it], pAp at [32+it]

#define WRED(x) { (x)+=__shfl_down((x),32); (x)+=__shfl_down((x),16); (x)+=__shfl_down((x),8); \
                  (x)+=__shfl_down((x),4);  (x)+=__shfl_down((x),2);  (x)+=__shfl_down((x),1); }

// ---------------------------------------------------------------------------
// Sinv[n,ky,kx] = 1 / (sum_c |D_c(ky,kx)|^2 + alpha_x/64); D from 5x5 psf DFT
// ---------------------------------------------------------------------------
__global__ __launch_bounds__(256) void k_sinv(const float* __restrict__ dict,
                                              const float* __restrict__ alpha_x,
                                              float* __restrict__ ws) {
  int idx = blockIdx.x * 256 + threadIdx.x;
  int n = blockIdx.y;
  if (idx >= HH * KXN) return;
  int ky = idx / KXN, kx = idx % KXN;
  float tr[25], ti[25];
  {
    float eyr[5], eyi[5], exr[5], exi[5];
#pragma unroll
    for (int a = 0; a < 5; ++a) {
      float s, c;
      sincosf(-2.0f * PI_F * (float)(ky * (a - 2)) / 128.0f, &s, &c);
      eyr[a] = c; eyi[a] = s;
      sincosf(-2.0f * PI_F * (float)(kx * (a - 2)) / 128.0f, &s, &c);
      exr[a] = c; exi[a] = s;
    }
#pragma unroll
    for (int a = 0; a < 5; ++a)
#pragma unroll
      for (int b = 0; b < 5; ++b) {
        tr[a*5+b] = eyr[a]*exr[b] - eyi[a]*exi[b];
        ti[a*5+b] = eyr[a]*exi[b] + eyi[a]*exr[b];
      }
  }
  const float* dn = dict + n * CIN * 25;
  float S = 0.0f;
  for (int c = 0; c < CIN; ++c) {
    const float* p = dn + c * 25;
    float Dr = 0.0f, Di = 0.0f;
#pragma unroll
    for (int t = 0; t < 25; ++t) { Dr += p[t]*tr[t]; Di += p[t]*ti[t]; }
    S += Dr*Dr + Di*Di;
  }
  float a = alpha_x[n] * (1.0f/64.0f);
  ws[OFF_SINV + (n*HH + ky)*KXN + kx] = 1.0f / (S + a);
}

// ---------------------------------------------------------------------------
// e[n,p] = y[n,p] - sum_c sum_{a,b} psf[n,c,a,b] * x[..circular..]
// ---------------------------------------------------------------------------
__global__ __launch_bounds__(256) void k_e(const float* __restrict__ x,
                                           const float* __restrict__ dict,
                                           const float* __restrict__ y,
                                           float* __restrict__ ws) {
  __shared__ float psf_s[CIN*25];
  __shared__ float xt[20*20];
  int n = blockIdx.y, tile = blockIdx.x, tid = threadIdx.x;
  int h0 = (tile >> 3) * 16, w0 = (tile & 7) * 16;
  for (int i = tid; i < CIN*25; i += 256) psf_s[i] = dict[n*CIN*25 + i];
  int py = tid >> 4, px = tid & 15;
  float acc = 0.0f;
  for (int c = 0; c < CIN; ++c) {
    __syncthreads();
    for (int i = tid; i < 400; i += 256) {
      int r = i / 20, cc = i % 20;
      int gh = (h0 + r - 2) & 127, gw = (w0 + cc - 2) & 127;
      xt[i] = x[((n*CIN + c)*HH + gh)*WW + gw];
    }
    __syncthreads();
    const float* pp = psf_s + c*25;
#pragma unroll
    for (int a = 0; a < 5; ++a)
#pragma unroll
      for (int b = 0; b < 5; ++b)
        acc += pp[a*5+b] * xt[(py+a)*20 + (px+b)];
  }
  int h = h0+py, w = w0+px;
  ws[OFF_E + (n*HH + h)*WW + w] = y[(n*HH + h)*WW + w] - acc;
}

// ---------------------------------------------------------------------------
// tiny table-DFT kernels (only 4 images each way)
// ---------------------------------------------------------------------------
__global__ __launch_bounds__(256) void k_fft_rows(float* __restrict__ ws) {
  __shared__ float twr[128], twi[128];
  int tid = threadIdx.x;
  if (tid < 128) { float s, c; sincosf(-2.0f*PI_F*(float)tid/128.0f, &s, &c); twr[tid]=c; twi[tid]=s; }
  __syncthreads();
  int idx = blockIdx.x*256 + tid, n = blockIdx.y;
  if (idx >= HH*KXN) return;
  int h = idx / KXN, k = idx % KXN;
  const float* row = ws + OFF_E + (n*HH + h)*WW;
  float sr = 0, si = 0;
  for (int w = 0; w < 128; ++w) {
    int t = (w*k) & 127;
    float v = row[w];
    sr += v*twr[t]; si += v*twi[t];
  }
  float* o = ws + OFF_ER + ((n*HH + h)*KXN + k)*2;
  o[0] = sr; o[1] = si;
}

__global__ __launch_bounds__(256) void k_fft_cols(float* __restrict__ ws) {
  __shared__ float twr[128], twi[128];
  int tid = threadIdx.x;
  if (tid < 128) { float s, c; sincosf(-2.0f*PI_F*(float)tid/128.0f, &s, &c); twr[tid]=c; twi[tid]=s; }
  __syncthreads();
  int idx = blockIdx.x*256 + tid, n = blockIdx.y;
  if (idx >= HH*KXN) return;
  int ky = idx / KXN, kx = idx % KXN;
  const float* Er = ws + OFF_ER + (size_t)n*HH*KXN*2;
  float sr = 0, si = 0;
  for (int h = 0; h < 128; ++h) {
    int t = (h*ky) & 127;
    float ar = Er[(h*KXN + kx)*2], ai = Er[(h*KXN + kx)*2 + 1];
    sr += ar*twr[t] - ai*twi[t];
    si += ar*twi[t] + ai*twr[t];
  }
  float sv = ws[OFF_SINV + (n*HH + ky)*KXN + kx];
  float* o = ws + OFF_EW + ((n*HH + ky)*KXN + kx)*2;
  o[0] = sr*sv; o[1] = si*sv;
}

__global__ __launch_bounds__(256) void k_ifft_cols(float* __restrict__ ws) {
  __shared__ float twr[128], twi[128];
  int tid = threadIdx.x;
  if (tid < 128) { float s, c; sincosf(-2.0f*PI_F*(float)tid/128.0f, &s, &c); twr[tid]=c; twi[tid]=s; }
  __syncthreads();
  int idx = blockIdx.x*256 + tid, n = blockIdx.y;
  if (idx >= HH*KXN) return;
  int h = idx / KXN, kx = idx % KXN;
  const float* EW = ws + OFF_EW + (size_t)n*HH*KXN*2;
  float sr = 0, si = 0;
  for (int ky = 0; ky < 128; ++ky) {
    int t = (h*ky) & 127;
    float ar = EW[(ky*KXN + kx)*2], ai = EW[(ky*KXN + kx)*2 + 1];
    sr += ar*twr[t] + ai*twi[t];
    si += ai*twr[t] - ar*twi[t];
  }
  float* o = ws + OFF_VR + ((n*HH + h)*KXN + kx)*2;
  o[0] = sr; o[1] = si;
}

__global__ __launch_bounds__(256) void k_ifft_rows(float* __restrict__ ws) {
  __shared__ float twr[128], twi[128];
  int tid = threadIdx.x;
  if (tid < 128) { float s, c; sincosf(-2.0f*PI_F*(float)tid/128.0f, &s, &c); twr[tid]=c; twi[tid]=s; }
  __syncthreads();
  int idx = blockIdx.x*256 + tid, n = blockIdx.y;
  int h = idx >> 7, w = idx & 127;
  const float* Vr = ws + OFF_VR + (size_t)n*HH*KXN*2;
  float s = 0.0f;
  for (int kx = 0; kx <= 64; ++kx) {
    int t = (w*kx) & 127;
    float ar = Vr[(h*KXN + kx)*2], ai = Vr[(h*KXN + kx)*2 + 1];
    float re = ar*twr[t] + ai*twi[t];
    s += (kx == 0 || kx == 64) ? re : 2.0f*re;
  }
  ws[OFF_WB + (n*HH + h)*WW + w] = s * (1.0f/16384.0f);
}

// ---------------------------------------------------------------------------
// x_new[n,c,p] = x[n,c,p] + sum_{a,b} psf[n,c,a,b]*wbuf[circ]
// ---------------------------------------------------------------------------
__global__ __launch_bounds__(256) void k_xnew(const float* __restrict__ x,
                                              const float* __restrict__ dict,
                                              const float* __restrict__ ws,
                                              float* __restrict__ out) {
  __shared__ float psf_s[CIN*25];
  __shared__ float wt[20*20];
  int n = blockIdx.y, tile = blockIdx.x, tid = threadIdx.x;
  int h0 = (tile >> 3) * 16, w0 = (tile & 7) * 16;
  for (int i = tid; i < CIN*25; i += 256) psf_s[i] = dict[n*CIN*25 + i];
  for (int i = tid; i < 400; i += 256) {
    int r = i / 20, cc = i % 20;
    int gh = (h0 + r - 2) & 127, gw = (w0 + cc - 2) & 127;
    wt[i] = ws[OFF_WB + (n*HH + gh)*WW + gw];
  }
  __syncthreads();
  int py = tid >> 4, px = tid & 15;
  int h = h0+py, w = w0+px;
  for (int c = 0; c < CIN; ++c) {
    float acc = 0.0f;
    const float* pp = psf_s + c*25;
#pragma unroll
    for (int a = 0; a < 5; ++a)
#pragma unroll
      for (int b = 0; b < 5; ++b)
        acc += pp[a*5+b] * wt[(py + 4 - a)*20 + (px + 4 - b)];
    int gi = ((n*CIN + c)*HH + h)*WW + w;
    out[gi] = x[gi] + acc;
  }
}

// ---------------------------------------------------------------------------
// R[n,i,j,u,v] = sum_{h,w} xnew_i[h+u-4, w+v-4] * xnew_j[h,w]  (zero-pad)
// v5: 8-wide column ownership (w0 = 8*(lane&15), rows via lane>>4), 16-dword
// windows (4 aligned b128) feed 72 FMA -> 18 FMA/b128. Wave w owns u={w,w+4};
// u=8 spread uniformly (wave w covers its it in {2w,2w+1}; LDS cross-reduce).
// NO occupancy floor -> no scratch spills (round-4 lesson: WRITE_SIZE 206MB).
// ---------------------------------------------------------------------------
__global__ __launch_bounds__(256) void k_corr(const float* __restrict__ xn,
                                              float* __restrict__ ws) {
  __shared__ float xi_s[40*136];
  __shared__ float red8[4][9];
  int n = blockIdx.y, p = blockIdx.x, tid = threadIdx.x;
  int ii = 0;
  while ((ii+1)*(ii+2)/2 <= p) ++ii;
  int jj = p - ii*(ii+1)/2;
  const float* Xi = xn + (size_t)(n*CIN + ii)*NPIX;
  const float* Xj = xn + (size_t)(n*CIN + jj)*NPIX;
  int wv = tid >> 6, lane = tid & 63;
  int l16 = lane & 15, rg = lane >> 4;   // 16 cols x 4 rows per wave
  int w0 = l16 << 3;                     // 8-wide column window
  const int uA = wv, uB = wv + 4;
  float accA[9], accB[9], accC[9];
#pragma unroll
  for (int t = 0; t < 9; ++t) { accA[t]=0.0f; accB[t]=0.0f; accC[t]=0.0f; }

  for (int q = 0; q < 4; ++q) {
    __syncthreads();
    for (int t = tid; t < 40*136; t += 256) {
      int r = t / 136, c = t % 136;
      int gh = q*32 - 4 + r, gw = c - 4;
      float v = 0.0f;
      if (gh >= 0 && gh < 128 && gw >= 0 && gw < 128) v = Xi[gh*128 + gw];
      xi_s[t] = v;
    }
    __syncthreads();
    for (int it = 0; it < 8; ++it) {
      int hl = it*4 + rg;                // 0..31 local output row
      int h = q*32 + hl;
      float xj[8];
      {
        const float4 t0 = *reinterpret_cast<const float4*>(Xj + h*128 + w0);
        const float4 t1 = *reinterpret_cast<const float4*>(Xj + h*128 + w0 + 4);
        xj[0]=t0.x; xj[1]=t0.y; xj[2]=t0.z; xj[3]=t0.w;
        xj[4]=t1.x; xj[5]=t1.y; xj[6]=t1.z; xj[7]=t1.w;
      }
      {
        const float* rp = &xi_s[(hl + uA)*136 + w0];
        const float4 a0 = *reinterpret_cast<const float4*>(rp);
        const float4 a1 = *reinterpret_cast<const float4*>(rp + 4);
        const float4 a2 = *reinterpret_cast<const float4*>(rp + 8);
        const float4 a3 = *reinterpret_cast<const float4*>(rp + 12);
        float xw[16] = {a0.x,a0.y,a0.z,a0.w, a1.x,a1.y,a1.z,a1.w,
                        a2.x,a2.y,a2.z,a2.w, a3.x,a3.y,a3.z,a3.w};
#pragma unroll
        for (int v = 0; v < 9; ++v)
#pragma unroll
          for (int k = 0; k < 8; ++k) accA[v] += xw[v+k]*xj[k];
      }
      {
        const float* rp = &xi_s[(hl + uB)*136 + w0];
        const float4 a0 = *reinterpret_cast<const float4*>(rp);
        const float4 a1 = *reinterpret_cast<const float4*>(rp + 4);
        const float4 a2 = *reinterpret_cast<const float4*>(rp + 8);
        const float4 a3 = *reinterpret_cast<const float4*>(rp + 12);
        float xw[16] = {a0.x,a0.y,a0.z,a0.w, a1.x,a1.y,a1.z,a1.w,
                        a2.x,a2.y,a2.z,a2.w, a3.x,a3.y,a3.z,a3.w};
#pragma unroll
        for (int v = 0; v < 9; ++v)
#pragma unroll
          for (int k = 0; k < 8; ++k) accB[v] += xw[v+k]*xj[k];
      }
      if ((it >> 1) == wv) {             // u=8, quarter duty per wave
        const float* rp = &xi_s[(hl + 8)*136 + w0];
        const float4 a0 = *reinterpret_cast<const float4*>(rp);
        const float4 a1 = *reinterpret_cast<const float4*>(rp + 4);
        const float4 a2 = *reinterpret_cast<const float4*>(rp + 8);
        const float4 a3 = *reinterpret_cast<const float4*>(rp + 12);
        float xw[16] = {a0.x,a0.y,a0.z,a0.w, a1.x,a1.y,a1.z,a1.w,
                        a2.x,a2.y,a2.z,a2.w, a3.x,a3.y,a3.z,a3.w};
#pragma unroll
        for (int v = 0; v < 9; ++v)
#pragma unroll
          for (int k = 0; k < 8; ++k) accC[v] += xw[v+k]*xj[k];
      }
    }
  }
  float* Rp = ws + OFF_R;
  size_t base  = (((size_t)n*CIN + ii)*CIN + jj)*81;
  size_t baseT = (((size_t)n*CIN + jj)*CIN + ii)*81;
#pragma unroll
  for (int v = 0; v < 9; ++v) { WRED(accA[v]); WRED(accB[v]); WRED(accC[v]); }
  if (lane == 0) {
#pragma unroll
    for (int v = 0; v < 9; ++v) red8[wv][v] = accC[v];
#pragma unroll
    for (int v = 0; v < 9; ++v) {
      int uv = uA*9 + v;
      Rp[base + uv] = accA[v];
      Rp[baseT + 80 - uv] = accA[v];
    }
#pragma unroll
    for (int v = 0; v < 9; ++v) {
      int uv = uB*9 + v;
      Rp[base + uv] = accB[v];
      Rp[baseT + 80 - uv] = accB[v];
    }
  }
  __syncthreads();
  if (tid < 9) {
    float s = red8[0][tid] + red8[1][tid] + red8[2][tid] + red8[3][tid];
    Rp[base + 72 + tid] = s;
    Rp[baseT + 8 - tid] = s;
  }
}

// ---------------------------------------------------------------------------
// Pm[n, i*25+u*5+v] = sum_{h,w} xnew[n,i,h+u-2,w+v-2]*y[n,h,w] + a_d*d[...]
// ---------------------------------------------------------------------------
__global__ __launch_bounds__(256) void k_pm(const float* __restrict__ xn,
                                            const float* __restrict__ y,
                                            const float* __restrict__ dict,
                                            const float* __restrict__ alpha_d,
                                            const float* __restrict__ regp,
                                            float* __restrict__ ws) {
  __shared__ float xt[20*20];
  __shared__ float red_s[4][25];
  int n = blockIdx.y, i = blockIdx.x, tid = threadIdx.x;
  int py = tid >> 4, px = tid & 15;
  float acc[25];
#pragma unroll
  for (int t = 0; t < 25; ++t) acc[t] = 0.0f;
  const float* Xi = xn + (size_t)(n*CIN + i)*NPIX;
  for (int tile = 0; tile < 64; ++tile) {
    int h0 = (tile >> 3)*16, w0 = (tile & 7)*16;
    __syncthreads();
    for (int t = tid; t < 400; t += 256) {
      int r = t / 20, cc = t % 20;
      int gh = h0 + r - 2, gw = w0 + cc - 2;
      float v = 0.0f;
      if (gh >= 0 && gh < 128 && gw >= 0 && gw < 128) v = Xi[gh*128 + gw];
      xt[t] = v;
    }
    __syncthreads();
    float yv = y[(n*HH + h0 + py)*WW + w0 + px];
#pragma unroll
    for (int u = 0; u < 5; ++u)
#pragma unroll
      for (int v = 0; v < 5; ++v)
        acc[u*5+v] += xt[(py+u)*20 + (px+v)] * yv;
  }
  int lane = tid & 63, wv = tid >> 6;
#pragma unroll
  for (int t = 0; t < 25; ++t) {
    float v = acc[t];
    WRED(v);
    if (lane == 0) red_s[wv][t] = v;
  }
  __syncthreads();
  if (tid < 25) {
    float s = red_s[0][tid] + red_s[1][tid] + red_s[2][tid] + red_s[3][tid];
    float ad = alpha_d[n] * 16384.0f * regp[0] * (1.0f/1600.0f);
    ws[OFF_PM + n*MMAT + i*25 + tid] = s + ad * dict[(n*CIN + i)*25 + tid];
  }
}

// ---------------------------------------------------------------------------
// CG on R directly (no explicit Q).
// (A v)[(j,a,c)] = sum_{i,b,d} R[n,i,j,(4+b-a),(4+d-c)] v[(i,b,d)] + reg*v
// ---------------------------------------------------------------------------
__global__ __launch_bounds__(256) void k_cg_zero(float* __restrict__ ws) {
  ws[OFF_SC + threadIdx.x] = 0.0f;
}

__global__ __launch_bounds__(256) void k_cg_init(float* __restrict__ ws) {
  int n = blockIdx.y, i = blockIdx.x*256 + threadIdx.x;
  float pval = 0.0f;
  if (i < MMAT) {
    pval = ws[OFF_PM + n*MMAT + i];
    ws[OFF_DV + n*MMAT + i] = 0.0f;
    ws[OFF_RV + n*MMAT + i] = pval;
    ws[OFF_PV + n*MMAT + i] = pval;
  }
  float part = pval*pval;
  WRED(part);
  __shared__ float red[4];
  int lane = threadIdx.x & 63, w = threadIdx.x >> 6;
  if (lane == 0) red[w] = part;
  __syncthreads();
  if (threadIdx.x == 0)
    atomicAdd(&ws[OFF_SC + n*64 + 0], red[0]+red[1]+red[2]+red[3]);
}

// Ap0 = Q p0, pAp0
__global__ __launch_bounds__(256) void k_cg_first(float* __restrict__ ws,
                                                  const float* __restrict__ alpha_d,
                                                  const float* __restrict__ regp) {
  __shared__ float vv[MMAT];
  __shared__ float part[25][66];
  int n = blockIdx.y, j = blockIdx.x, tid = threadIdx.x;
  for (int t = tid; t < MMAT; t += 256) vv[t] = ws[OFF_PV + n*MMAT + t];
  __syncthreads();
  int i = tid & 63, qq = tid >> 6;
  const float* Rij = ws + OFF_R + (((size_t)n*CIN + i)*CIN + j)*81;
  const float* vi = &vv[i*25];
#pragma unroll
  for (int s6 = 0; s6 < 7; ++s6) {
    int ac = qq + 4*s6;
    if (ac < 25) {
      int a = ac/5, c = ac%5;
      float s = 0.0f;
#pragma unroll
      for (int b = 0; b < 5; ++b)
#pragma unroll
        for (int d = 0; d < 5; ++d)
          s += Rij[(4+b-a)*9 + (4+d-c)] * vi[b*5+d];
      part[ac][i] = s;
    }
  }
  __syncthreads();
  float contrib = 0.0f;
  if (tid < 25) {
    float s = 0.0f;
    for (int t = 0; t < 64; ++t) s += part[tid][t];
    float reg = alpha_d[n] * 16384.0f * regp[0] * (1.0f/1600.0f);
    s += reg * vv[j*25 + tid];
    ws[OFF_AP + n*MMAT + j*25 + tid] = s;
    contrib = s * vv[j*25 + tid];
  }
  if (tid < 64) {
    WRED(contrib);
    if (tid == 0) atomicAdd(&ws[OFF_SC + n*64 + 32 + 0], contrib);
  }
}

// p' = r + beta p; Ap' = A r + beta Ap; pAp[it+1] += p'.Ap'
__global__ __launch_bounds__(256) void k_cg_step(float* __restrict__ ws, int it,
                                                 const float* __restrict__ alpha_d,
                                                 const float* __restrict__ regp) {
  __shared__ float vv[MMAT];   // r
  __shared__ float part[25][66];
  int n = blockIdx.y, j = blockIdx.x, tid = threadIdx.x;
  for (int t = tid; t < MMAT; t += 256) vv[t] = ws[OFF_RV + n*MMAT + t];
  __syncthreads();
  int i = tid & 63, qq = tid >> 6;
  const float* Rij = ws + OFF_R + (((size_t)n*CIN + i)*CIN + j)*81;
  const float* vi = &vv[i*25];
#pragma unroll
  for (int s6 = 0; s6 < 7; ++s6) {
    int ac = qq + 4*s6;
    if (ac < 25) {
      int a = ac/5, c = ac%5;
      float s = 0.0f;
#pragma unroll
      for (int b = 0; b < 5; ++b)
#pragma unroll
        for (int d = 0; d < 5; ++d)
          s += Rij[(4+b-a)*9 + (4+d-c)] * vi[b*5+d];
      part[ac][i] = s;
    }
  }
  __syncthreads();
  float contrib = 0.0f;
  if (tid < 25) {
    float s = 0.0f;
    for (int t = 0; t < 64; ++t) s += part[tid][t];
    float reg = alpha_d[n] * 16384.0f * regp[0] * (1.0f/1600.0f);
    s += reg * vv[j*25 + tid];                 // s = (Q r)[j*25+tid]
    float beta = ws[OFF_SC + n*64 + it + 1] / (ws[OFF_SC + n*64 + it] + 1e-30f);
    int idx = n*MMAT + j*25 + tid;
    float pn  = vv[j*25 + tid] + beta * ws[OFF_PV + idx];
    float apn = s + beta * ws[OFF_AP + idx];
    ws[OFF_PV + idx] = pn;
    ws[OFF_AP + idx] = apn;
    contrib = pn * apn;
  }
  if (tid < 64) {
    WRED(contrib);
    if (tid == 0) atomicAdd(&ws[OFF_SC + n*64 + 32 + (it+1)], contrib);
  }
}

// alpha = rr[it]/pAp[it]; d += alpha p; r -= alpha Ap; rr[it+1] += r'.r'
__global__ __launch_bounds__(256) void k_cg_upd(float* __restrict__ ws, int it,
                                                int last, float* __restrict__ out) {
  int n = blockIdx.y, i = blockIdx.x*256 + threadIdx.x;
  float rr  = ws[OFF_SC + n*64 + it];
  float pap = ws[OFF_SC + n*64 + 32 + it];
  float alpha = rr / (pap + 1e-30f);
  float rn = 0.0f;
  if (i < MMAT) {
    float dv = ws[OFF_DV + n*MMAT + i] + alpha * ws[OFF_PV + n*MMAT + i];
    rn = ws[OFF_RV + n*MMAT + i] - alpha * ws[OFF_AP + n*MMAT + i];
    ws[OFF_DV + n*MMAT + i] = dv;
    ws[OFF_RV + n*MMAT + i] = rn;
    if (last) out[4194304 + n*MMAT + i] = dv;
  }
  float part = rn*rn;
  WRED(part);
  __shared__ float red[4];
  int lane = threadIdx.x & 63, w = threadIdx.x >> 6;
  if (lane == 0) red[w] = part;
  __syncthreads();
  if (threadIdx.x == 0)
    atomicAdd(&ws[OFF_SC + n*64 + it + 1], red[0]+red[1]+red[2]+red[3]);
}

// ---------------------------------------------------------------------------
extern "C" void kernel_launch(void* const* d_in, const int* in_sizes, int n_in,
                              void* d_out, int out_size, void* d_ws, size_t ws_size,
                              hipStream_t stream) {
  (void)in_sizes; (void)n_in; (void)out_size; (void)ws_size;
  const float* x    = (const float*)d_in[0];
  const float* dict = (const float*)d_in[1];
  const float* y    = (const float*)d_in[2];
  const float* ax   = (const float*)d_in[3];
  const float* ad   = (const float*)d_in[4];
  const float* regp = (const float*)d_in[5];
  float* out = (float*)d_out;
  float* ws  = (float*)d_ws;   // needs ~6.8 MB

  dim3 b256(256);
  k_sinv<<<dim3(33,4), b256, 0, stream>>>(dict, ax, ws);
  k_e<<<dim3(64,4), b256, 0, stream>>>(x, dict, y, ws);
  k_fft_rows<<<dim3(33,4), b256, 0, stream>>>(ws);
  k_fft_cols<<<dim3(33,4), b256, 0, stream>>>(ws);
  k_ifft_cols<<<dim3(33,4), b256, 0, stream>>>(ws);
  k_ifft_rows<<<dim3(64,4), b256, 0, stream>>>(ws);
  k_xnew<<<dim3(64,4), b256, 0, stream>>>(x, dict, ws, out);
  k_corr<<<dim3(2080,4), b256, 0, stream>>>(out, ws);
  k_pm<<<dim3(64,4), b256, 0, stream>>>(out, y, dict, ad, regp, ws);

  // ---- CG solve (R-direct matvec, fused p/Ap recurrence) ----
  k_cg_zero<<<dim3(1), b256, 0, stream>>>(ws);
  k_cg_init<<<dim3(7,4), b256, 0, stream>>>(ws);
  k_cg_first<<<dim3(64,4), b256, 0, stream>>>(ws, ad, regp);
  for (int it = 0; it < NIT; ++it) {
    k_cg_upd<<<dim3(7,4), b256, 0, stream>>>(ws, it, (it == NIT-1) ? 1 : 0, out);
    if (it < NIT-1)
      k_cg_step<<<dim3(64,4), b256, 0, stream>>>(ws, it, ad, regp);
  }
}

// Round 6
// 918.859 us; speedup vs baseline: 1.6314x; 1.6314x over previous
//
#include <hip/hip_runtime.h>
#include <math.h>

#define PI_F 3.14159265358979323846f

#define NS   4
#define CIN  64
#define HH   128
#define WW   128
#define KXN  65          // rfft last-axis size
#define NPIX (HH*WW)
#define MMAT 1600        // CIN*5*5
#define NIT  10          // CG iterations

// float offsets in workspace (~6.8 MB)
#define OFF_SINV 0
#define OFF_E    33280
#define OFF_ER   98816
#define OFF_EW   165376
#define OFF_VR   231936
#define OFF_WB   298496
#define OFF_R    364032      // 4*64*64*81 = 1,327,104 floats
#define OFF_PM   1691136    // 6400 floats
// CG state reuses the (dead-by-then) front-end scratch at offset 0:
#define OFF_DV   0
#define OFF_RV   6400
#define OFF_PV   12800
#define OFF_AP   19200
#define OFF_SC   25600      // per-sample 64 slots: rr at [it], pAp at [32+it]

#define WRED(x) { (x)+=__shfl_down((x),32); (x)+=__shfl_down((x),16); (x)+=__shfl_down((x),8); \
                  (x)+=__shfl_down((x),4);  (x)+=__shfl_down((x),2);  (x)+=__shfl_down((x),1); }

// ---------------------------------------------------------------------------
// Sinv[n,ky,kx] = 1 / (sum_c |D_c(ky,kx)|^2 + alpha_x/64); D from 5x5 psf DFT
// ---------------------------------------------------------------------------
__global__ __launch_bounds__(256) void k_sinv(const float* __restrict__ dict,
                                              const float* __restrict__ alpha_x,
                                              float* __restrict__ ws) {
  int idx = blockIdx.x * 256 + threadIdx.x;
  int n = blockIdx.y;
  if (idx >= HH * KXN) return;
  int ky = idx / KXN, kx = idx % KXN;
  float tr[25], ti[25];
  {
    float eyr[5], eyi[5], exr[5], exi[5];
#pragma unroll
    for (int a = 0; a < 5; ++a) {
      float s, c;
      sincosf(-2.0f * PI_F * (float)(ky * (a - 2)) / 128.0f, &s, &c);
      eyr[a] = c; eyi[a] = s;
      sincosf(-2.0f * PI_F * (float)(kx * (a - 2)) / 128.0f, &s, &c);
      exr[a] = c; exi[a] = s;
    }
#pragma unroll
    for (int a = 0; a < 5; ++a)
#pragma unroll
      for (int b = 0; b < 5; ++b) {
        tr[a*5+b] = eyr[a]*exr[b] - eyi[a]*exi[b];
        ti[a*5+b] = eyr[a]*exi[b] + eyi[a]*exr[b];
      }
  }
  const float* dn = dict + n * CIN * 25;
  float S = 0.0f;
  for (int c = 0; c < CIN; ++c) {
    const float* p = dn + c * 25;
    float Dr = 0.0f, Di = 0.0f;
#pragma unroll
    for (int t = 0; t < 25; ++t) { Dr += p[t]*tr[t]; Di += p[t]*ti[t]; }
    S += Dr*Dr + Di*Di;
  }
  float a = alpha_x[n] * (1.0f/64.0f);
  ws[OFF_SINV + (n*HH + ky)*KXN + kx] = 1.0f / (S + a);
}

// ---------------------------------------------------------------------------
// e[n,p] = y[n,p] - sum_c sum_{a,b} psf[n,c,a,b] * x[..circular..]
// ---------------------------------------------------------------------------
__global__ __launch_bounds__(256) void k_e(const float* __restrict__ x,
                                           const float* __restrict__ dict,
                                           const float* __restrict__ y,
                                           float* __restrict__ ws) {
  __shared__ float psf_s[CIN*25];
  __shared__ float xt[20*20];
  int n = blockIdx.y, tile = blockIdx.x, tid = threadIdx.x;
  int h0 = (tile >> 3) * 16, w0 = (tile & 7) * 16;
  for (int i = tid; i < CIN*25; i += 256) psf_s[i] = dict[n*CIN*25 + i];
  int py = tid >> 4, px = tid & 15;
  float acc = 0.0f;
  for (int c = 0; c < CIN; ++c) {
    __syncthreads();
    for (int i = tid; i < 400; i += 256) {
      int r = i / 20, cc = i % 20;
      int gh = (h0 + r - 2) & 127, gw = (w0 + cc - 2) & 127;
      xt[i] = x[((n*CIN + c)*HH + gh)*WW + gw];
    }
    __syncthreads();
    const float* pp = psf_s + c*25;
#pragma unroll
    for (int a = 0; a < 5; ++a)
#pragma unroll
      for (int b = 0; b < 5; ++b)
        acc += pp[a*5+b] * xt[(py+a)*20 + (px+b)];
  }
  int h = h0+py, w = w0+px;
  ws[OFF_E + (n*HH + h)*WW + w] = y[(n*HH + h)*WW + w] - acc;
}

// ---------------------------------------------------------------------------
// tiny table-DFT kernels (only 4 images each way)
// ---------------------------------------------------------------------------
__global__ __launch_bounds__(256) void k_fft_rows(float* __restrict__ ws) {
  __shared__ float twr[128], twi[128];
  int tid = threadIdx.x;
  if (tid < 128) { float s, c; sincosf(-2.0f*PI_F*(float)tid/128.0f, &s, &c); twr[tid]=c; twi[tid]=s; }
  __syncthreads();
  int idx = blockIdx.x*256 + tid, n = blockIdx.y;
  if (idx >= HH*KXN) return;
  int h = idx / KXN, k = idx % KXN;
  const float* row = ws + OFF_E + (n*HH + h)*WW;
  float sr = 0, si = 0;
  for (int w = 0; w < 128; ++w) {
    int t = (w*k) & 127;
    float v = row[w];
    sr += v*twr[t]; si += v*twi[t];
  }
  float* o = ws + OFF_ER + ((n*HH + h)*KXN + k)*2;
  o[0] = sr; o[1] = si;
}

__global__ __launch_bounds__(256) void k_fft_cols(float* __restrict__ ws) {
  __shared__ float twr[128], twi[128];
  int tid = threadIdx.x;
  if (tid < 128) { float s, c; sincosf(-2.0f*PI_F*(float)tid/128.0f, &s, &c); twr[tid]=c; twi[tid]=s; }
  __syncthreads();
  int idx = blockIdx.x*256 + tid, n = blockIdx.y;
  if (idx >= HH*KXN) return;
  int ky = idx / KXN, kx = idx % KXN;
  const float* Er = ws + OFF_ER + (size_t)n*HH*KXN*2;
  float sr = 0, si = 0;
  for (int h = 0; h < 128; ++h) {
    int t = (h*ky) & 127;
    float ar = Er[(h*KXN + kx)*2], ai = Er[(h*KXN + kx)*2 + 1];
    sr += ar*twr[t] - ai*twi[t];
    si += ar*twi[t] + ai*twr[t];
  }
  float sv = ws[OFF_SINV + (n*HH + ky)*KXN + kx];
  float* o = ws + OFF_EW + ((n*HH + ky)*KXN + kx)*2;
  o[0] = sr*sv; o[1] = si*sv;
}

__global__ __launch_bounds__(256) void k_ifft_cols(float* __restrict__ ws) {
  __shared__ float twr[128], twi[128];
  int tid = threadIdx.x;
  if (tid < 128) { float s, c; sincosf(-2.0f*PI_F*(float)tid/128.0f, &s, &c); twr[tid]=c; twi[tid]=s; }
  __syncthreads();
  int idx = blockIdx.x*256 + tid, n = blockIdx.y;
  if (idx >= HH*KXN) return;
  int h = idx / KXN, kx = idx % KXN;
  const float* EW = ws + OFF_EW + (size_t)n*HH*KXN*2;
  float sr = 0, si = 0;
  for (int ky = 0; ky < 128; ++ky) {
    int t = (h*ky) & 127;
    float ar = EW[(ky*KXN + kx)*2], ai = EW[(ky*KXN + kx)*2 + 1];
    sr += ar*twr[t] + ai*twi[t];
    si += ai*twr[t] - ar*twi[t];
  }
  float* o = ws + OFF_VR + ((n*HH + h)*KXN + kx)*2;
  o[0] = sr; o[1] = si;
}

__global__ __launch_bounds__(256) void k_ifft_rows(float* __restrict__ ws) {
  __shared__ float twr[128], twi[128];
  int tid = threadIdx.x;
  if (tid < 128) { float s, c; sincosf(-2.0f*PI_F*(float)tid/128.0f, &s, &c); twr[tid]=c; twi[tid]=s; }
  __syncthreads();
  int idx = blockIdx.x*256 + tid, n = blockIdx.y;
  int h = idx >> 7, w = idx & 127;
  const float* Vr = ws + OFF_VR + (size_t)n*HH*KXN*2;
  float s = 0.0f;
  for (int kx = 0; kx <= 64; ++kx) {
    int t = (w*kx) & 127;
    float ar = Vr[(h*KXN + kx)*2], ai = Vr[(h*KXN + kx)*2 + 1];
    float re = ar*twr[t] + ai*twi[t];
    s += (kx == 0 || kx == 64) ? re : 2.0f*re;
  }
  ws[OFF_WB + (n*HH + h)*WW + w] = s * (1.0f/16384.0f);
}

// ---------------------------------------------------------------------------
// x_new[n,c,p] = x[n,c,p] + sum_{a,b} psf[n,c,a,b]*wbuf[circ]
// ---------------------------------------------------------------------------
__global__ __launch_bounds__(256) void k_xnew(const float* __restrict__ x,
                                              const float* __restrict__ dict,
                                              const float* __restrict__ ws,
                                              float* __restrict__ out) {
  __shared__ float psf_s[CIN*25];
  __shared__ float wt[20*20];
  int n = blockIdx.y, tile = blockIdx.x, tid = threadIdx.x;
  int h0 = (tile >> 3) * 16, w0 = (tile & 7) * 16;
  for (int i = tid; i < CIN*25; i += 256) psf_s[i] = dict[n*CIN*25 + i];
  for (int i = tid; i < 400; i += 256) {
    int r = i / 20, cc = i % 20;
    int gh = (h0 + r - 2) & 127, gw = (w0 + cc - 2) & 127;
    wt[i] = ws[OFF_WB + (n*HH + gh)*WW + gw];
  }
  __syncthreads();
  int py = tid >> 4, px = tid & 15;
  int h = h0+py, w = w0+px;
  for (int c = 0; c < CIN; ++c) {
    float acc = 0.0f;
    const float* pp = psf_s + c*25;
#pragma unroll
    for (int a = 0; a < 5; ++a)
#pragma unroll
      for (int b = 0; b < 5; ++b)
        acc += pp[a*5+b] * wt[(py + 4 - a)*20 + (px + 4 - b)];
    int gi = ((n*CIN + c)*HH + h)*WW + w;
    out[gi] = x[gi] + acc;
  }
}

// ---------------------------------------------------------------------------
// R[n,i,j,u,v] = sum_{h,w} xnew_i[h+u-4, w+v-4] * xnew_j[h,w]  (zero-pad)
// v6: J=2 channel pairs per block (window reuse x2), lane-consecutive 4-wide
// windows (m97-pattern, conflict-free: w0 = ch*64 + 4*l16), u-split across
// waves (u in {w, w+4}; u=8 rotating duty -> small acc, no spills).
// ---------------------------------------------------------------------------
__global__ __launch_bounds__(256) void k_corr(const float* __restrict__ xn,
                                              float* __restrict__ ws) {
  __shared__ float xi_s[40*136];
  __shared__ float red8[4][2][9];
  int n = blockIdx.y, p = blockIdx.x, tid = threadIdx.x;
  // decode pair-block p -> (ii, jb): jb in 0..ii/2
  int ii = 0, cum = 0;
  while (cum + (ii >> 1) + 1 <= p) { cum += (ii >> 1) + 1; ++ii; }
  int jb = p - cum;
  int j0 = 2*jb;
  int j1 = 2*jb + 1;
  int j1ok = (j1 <= ii) ? 1 : 0;
  int j1r = (j1 <= 63) ? j1 : 63;     // clamp for safe (unused) loads
  const float* Xi  = xn + (size_t)(n*CIN + ii)*NPIX;
  const float* Xj0 = xn + (size_t)(n*CIN + j0)*NPIX;
  const float* Xj1 = xn + (size_t)(n*CIN + j1r)*NPIX;
  int wv = tid >> 6, lane = tid & 63;
  int l16 = lane & 15, rg = lane >> 4;   // 16 col-chunks x 4 rows per wave
  const int uA = wv, uB = wv + 4;
  float accA[2][9], accB[2][9], accC[2][9];
#pragma unroll
  for (int v = 0; v < 9; ++v) {
    accA[0][v]=0.0f; accA[1][v]=0.0f;
    accB[0][v]=0.0f; accB[1][v]=0.0f;
    accC[0][v]=0.0f; accC[1][v]=0.0f;
  }

  for (int q = 0; q < 4; ++q) {
    __syncthreads();
    for (int t = tid; t < 40*136; t += 256) {
      int r = t / 136, c = t % 136;
      int gh = q*32 - 4 + r, gw = c - 4;
      float v = 0.0f;
      if (gh >= 0 && gh < 128 && gw >= 0 && gw < 128) v = Xi[gh*128 + gw];
      xi_s[t] = v;
    }
    __syncthreads();
#pragma unroll
    for (int ch = 0; ch < 2; ++ch) {
      int wbase = ch*64 + (l16 << 2);
      for (int it = 0; it < 8; ++it) {
        int hl = (it << 2) + rg;             // 0..31 local output row
        int grow = (q*32 + hl)*128 + wbase;
        const float4 xj0v = *reinterpret_cast<const float4*>(Xj0 + grow);
        const float4 xj1v = *reinterpret_cast<const float4*>(Xj1 + grow);
        float xj0[4] = {xj0v.x, xj0v.y, xj0v.z, xj0v.w};
        float xj1[4] = {xj1v.x, xj1v.y, xj1v.z, xj1v.w};
        {
          const float* rp = &xi_s[(hl + uA)*136 + wbase];
          const float4 a0 = *reinterpret_cast<const float4*>(rp);
          const float4 a1 = *reinterpret_cast<const float4*>(rp + 4);
          const float4 a2 = *reinterpret_cast<const float4*>(rp + 8);
          float xw[12] = {a0.x,a0.y,a0.z,a0.w, a1.x,a1.y,a1.z,a1.w, a2.x,a2.y,a2.z,a2.w};
#pragma unroll
          for (int v = 0; v < 9; ++v)
#pragma unroll
            for (int k = 0; k < 4; ++k) {
              accA[0][v] += xw[v+k]*xj0[k];
              accA[1][v] += xw[v+k]*xj1[k];
            }
        }
        {
          const float* rp = &xi_s[(hl + uB)*136 + wbase];
          const float4 a0 = *reinterpret_cast<const float4*>(rp);
          const float4 a1 = *reinterpret_cast<const float4*>(rp + 4);
          const float4 a2 = *reinterpret_cast<const float4*>(rp + 8);
          float xw[12] = {a0.x,a0.y,a0.z,a0.w, a1.x,a1.y,a1.z,a1.w, a2.x,a2.y,a2.z,a2.w};
#pragma unroll
          for (int v = 0; v < 9; ++v)
#pragma unroll
            for (int k = 0; k < 4; ++k) {
              accB[0][v] += xw[v+k]*xj0[k];
              accB[1][v] += xw[v+k]*xj1[k];
            }
        }
        if ((it >> 1) == wv) {               // u=8, rotating duty
          const float* rp = &xi_s[(hl + 8)*136 + wbase];
          const float4 a0 = *reinterpret_cast<const float4*>(rp);
          const float4 a1 = *reinterpret_cast<const float4*>(rp + 4);
          const float4 a2 = *reinterpret_cast<const float4*>(rp + 8);
          float xw[12] = {a0.x,a0.y,a0.z,a0.w, a1.x,a1.y,a1.z,a1.w, a2.x,a2.y,a2.z,a2.w};
#pragma unroll
          for (int v = 0; v < 9; ++v)
#pragma unroll
            for (int k = 0; k < 4; ++k) {
              accC[0][v] += xw[v+k]*xj0[k];
              accC[1][v] += xw[v+k]*xj1[k];
            }
        }
      }
    }
  }
  // wave-level reduction (each wave covered the full image for its u-set)
#pragma unroll
  for (int v = 0; v < 9; ++v) {
    WRED(accA[0][v]); WRED(accA[1][v]);
    WRED(accB[0][v]); WRED(accB[1][v]);
    WRED(accC[0][v]); WRED(accC[1][v]);
  }
  float* Rp = ws + OFF_R;
  size_t b0  = (((size_t)n*CIN + ii)*CIN + j0)*81;
  size_t b0T = (((size_t)n*CIN + j0)*CIN + ii)*81;
  size_t b1  = (((size_t)n*CIN + ii)*CIN + j1r)*81;
  size_t b1T = (((size_t)n*CIN + j1r)*CIN + ii)*81;
  if (lane == 0) {
#pragma unroll
    for (int v = 0; v < 9; ++v) {
      red8[wv][0][v] = accC[0][v];
      red8[wv][1][v] = accC[1][v];
    }
#pragma unroll
    for (int v = 0; v < 9; ++v) {
      int uv = uA*9 + v;
      Rp[b0 + uv] = accA[0][v];
      Rp[b0T + 80 - uv] = accA[0][v];
      if (j1ok) { Rp[b1 + uv] = accA[1][v]; Rp[b1T + 80 - uv] = accA[1][v]; }
    }
#pragma unroll
    for (int v = 0; v < 9; ++v) {
      int uv = uB*9 + v;
      Rp[b0 + uv] = accB[0][v];
      Rp[b0T + 80 - uv] = accB[0][v];
      if (j1ok) { Rp[b1 + uv] = accB[1][v]; Rp[b1T + 80 - uv] = accB[1][v]; }
    }
  }
  __syncthreads();
  if (tid < 9) {
    float s = red8[0][0][tid] + red8[1][0][tid] + red8[2][0][tid] + red8[3][0][tid];
    Rp[b0 + 72 + tid] = s;
    Rp[b0T + 8 - tid] = s;
  } else if (tid >= 16 && tid < 25 && j1ok) {
    int v = tid - 16;
    float s = red8[0][1][v] + red8[1][1][v] + red8[2][1][v] + red8[3][1][v];
    Rp[b1 + 72 + v] = s;
    Rp[b1T + 8 - v] = s;
  }
}

// ---------------------------------------------------------------------------
// Pm[n, i*25+u*5+v] = sum_{h,w} xnew[n,i,h+u-2,w+v-2]*y[n,h,w] + a_d*d[...]
// ---------------------------------------------------------------------------
__global__ __launch_bounds__(256) void k_pm(const float* __restrict__ xn,
                                            const float* __restrict__ y,
                                            const float* __restrict__ dict,
                                            const float* __restrict__ alpha_d,
                                            const float* __restrict__ regp,
                                            float* __restrict__ ws) {
  __shared__ float xt[20*20];
  __shared__ float red_s[4][25];
  int n = blockIdx.y, i = blockIdx.x, tid = threadIdx.x;
  int py = tid >> 4, px = tid & 15;
  float acc[25];
#pragma unroll
  for (int t = 0; t < 25; ++t) acc[t] = 0.0f;
  const float* Xi = xn + (size_t)(n*CIN + i)*NPIX;
  for (int tile = 0; tile < 64; ++tile) {
    int h0 = (tile >> 3)*16, w0 = (tile & 7)*16;
    __syncthreads();
    for (int t = tid; t < 400; t += 256) {
      int r = t / 20, cc = t % 20;
      int gh = h0 + r - 2, gw = w0 + cc - 2;
      float v = 0.0f;
      if (gh >= 0 && gh < 128 && gw >= 0 && gw < 128) v = Xi[gh*128 + gw];
      xt[t] = v;
    }
    __syncthreads();
    float yv = y[(n*HH + h0 + py)*WW + w0 + px];
#pragma unroll
    for (int u = 0; u < 5; ++u)
#pragma unroll
      for (int v = 0; v < 5; ++v)
        acc[u*5+v] += xt[(py+u)*20 + (px+v)] * yv;
  }
  int lane = tid & 63, wv = tid >> 6;
#pragma unroll
  for (int t = 0; t < 25; ++t) {
    float v = acc[t];
    WRED(v);
    if (lane == 0) red_s[wv][t] = v;
  }
  __syncthreads();
  if (tid < 25) {
    float s = red_s[0][tid] + red_s[1][tid] + red_s[2][tid] + red_s[3][tid];
    float ad = alpha_d[n] * 16384.0f * regp[0] * (1.0f/1600.0f);
    ws[OFF_PM + n*MMAT + i*25 + tid] = s + ad * dict[(n*CIN + i)*25 + tid];
  }
}

// ---------------------------------------------------------------------------
// CG on R directly (no explicit Q).
// (A v)[(j,a,c)] = sum_{i,b,d} R[n,i,j,(4+b-a),(4+d-c)] v[(i,b,d)] + reg*v
// ---------------------------------------------------------------------------
__global__ __launch_bounds__(256) void k_cg_zero(float* __restrict__ ws) {
  ws[OFF_SC + threadIdx.x] = 0.0f;
}

__global__ __launch_bounds__(256) void k_cg_init(float* __restrict__ ws) {
  int n = blockIdx.y, i = blockIdx.x*256 + threadIdx.x;
  float pval = 0.0f;
  if (i < MMAT) {
    pval = ws[OFF_PM + n*MMAT + i];
    ws[OFF_DV + n*MMAT + i] = 0.0f;
    ws[OFF_RV + n*MMAT + i] = pval;
    ws[OFF_PV + n*MMAT + i] = pval;
  }
  float part = pval*pval;
  WRED(part);
  __shared__ float red[4];
  int lane = threadIdx.x & 63, w = threadIdx.x >> 6;
  if (lane == 0) red[w] = part;
  __syncthreads();
  if (threadIdx.x == 0)
    atomicAdd(&ws[OFF_SC + n*64 + 0], red[0]+red[1]+red[2]+red[3]);
}

// Ap0 = Q p0, pAp0
__global__ __launch_bounds__(256) void k_cg_first(float* __restrict__ ws,
                                                  const float* __restrict__ alpha_d,
                                                  const float* __restrict__ regp) {
  __shared__ float vv[MMAT];
  __shared__ float part[25][66];
  int n = blockIdx.y, j = blockIdx.x, tid = threadIdx.x;
  for (int t = tid; t < MMAT; t += 256) vv[t] = ws[OFF_PV + n*MMAT + t];
  __syncthreads();
  int i = tid & 63, qq = tid >> 6;
  const float* Rij = ws + OFF_R + (((size_t)n*CIN + i)*CIN + j)*81;
  const float* vi = &vv[i*25];
#pragma unroll
  for (int s6 = 0; s6 < 7; ++s6) {
    int ac = qq + 4*s6;
    if (ac < 25) {
      int a = ac/5, c = ac%5;
      float s = 0.0f;
#pragma unroll
      for (int b = 0; b < 5; ++b)
#pragma unroll
        for (int d = 0; d < 5; ++d)
          s += Rij[(4+b-a)*9 + (4+d-c)] * vi[b*5+d];
      part[ac][i] = s;
    }
  }
  __syncthreads();
  float contrib = 0.0f;
  if (tid < 25) {
    float s = 0.0f;
    for (int t = 0; t < 64; ++t) s += part[tid][t];
    float reg = alpha_d[n] * 16384.0f * regp[0] * (1.0f/1600.0f);
    s += reg * vv[j*25 + tid];
    ws[OFF_AP + n*MMAT + j*25 + tid] = s;
    contrib = s * vv[j*25 + tid];
  }
  if (tid < 64) {
    WRED(contrib);
    if (tid == 0) atomicAdd(&ws[OFF_SC + n*64 + 32 + 0], contrib);
  }
}

// p' = r + beta p; Ap' = A r + beta Ap; pAp[it+1] += p'.Ap'
__global__ __launch_bounds__(256) void k_cg_step(float* __restrict__ ws, int it,
                                                 const float* __restrict__ alpha_d,
                                                 const float* __restrict__ regp) {
  __shared__ float vv[MMAT];   // r
  __shared__ float part[25][66];
  int n = blockIdx.y, j = blockIdx.x, tid = threadIdx.x;
  for (int t = tid; t < MMAT; t += 256) vv[t] = ws[OFF_RV + n*MMAT + t];
  __syncthreads();
  int i = tid & 63, qq = tid >> 6;
  const float* Rij = ws + OFF_R + (((size_t)n*CIN + i)*CIN + j)*81;
  const float* vi = &vv[i*25];
#pragma unroll
  for (int s6 = 0; s6 < 7; ++s6) {
    int ac = qq + 4*s6;
    if (ac < 25) {
      int a = ac/5, c = ac%5;
      float s = 0.0f;
#pragma unroll
      for (int b = 0; b < 5; ++b)
#pragma unroll
        for (int d = 0; d < 5; ++d)
          s += Rij[(4+b-a)*9 + (4+d-c)] * vi[b*5+d];
      part[ac][i] = s;
    }
  }
  __syncthreads();
  float contrib = 0.0f;
  if (tid < 25) {
    float s = 0.0f;
    for (int t = 0; t < 64; ++t) s += part[tid][t];
    float reg = alpha_d[n] * 16384.0f * regp[0] * (1.0f/1600.0f);
    s += reg * vv[j*25 + tid];                 // s = (Q r)[j*25+tid]
    float beta = ws[OFF_SC + n*64 + it + 1] / (ws[OFF_SC + n*64 + it] + 1e-30f);
    int idx = n*MMAT + j*25 + tid;
    float pn  = vv[j*25 + tid] + beta * ws[OFF_PV + idx];
    float apn = s + beta * ws[OFF_AP + idx];
    ws[OFF_PV + idx] = pn;
    ws[OFF_AP + idx] = apn;
    contrib = pn * apn;
  }
  if (tid < 64) {
    WRED(contrib);
    if (tid == 0) atomicAdd(&ws[OFF_SC + n*64 + 32 + (it+1)], contrib);
  }
}

// alpha = rr[it]/pAp[it]; d += alpha p; r -= alpha Ap; rr[it+1] += r'.r'
__global__ __launch_bounds__(256) void k_cg_upd(float* __restrict__ ws, int it,
                                                int last, float* __restrict__ out) {
  int n = blockIdx.y, i = blockIdx.x*256 + threadIdx.x;
  float rr  = ws[OFF_SC + n*64 + it];
  float pap = ws[OFF_SC + n*64 + 32 + it];
  float alpha = rr / (pap + 1e-30f);
  float rn = 0.0f;
  if (i < MMAT) {
    float dv = ws[OFF_DV + n*MMAT + i] + alpha * ws[OFF_PV + n*MMAT + i];
    rn = ws[OFF_RV + n*MMAT + i] - alpha * ws[OFF_AP + n*MMAT + i];
    ws[OFF_DV + n*MMAT + i] = dv;
    ws[OFF_RV + n*MMAT + i] = rn;
    if (last) out[4194304 + n*MMAT + i] = dv;
  }
  float part = rn*rn;
  WRED(part);
  __shared__ float red[4];
  int lane = threadIdx.x & 63, w = threadIdx.x >> 6;
  if (lane == 0) red[w] = part;
  __syncthreads();
  if (threadIdx.x == 0)
    atomicAdd(&ws[OFF_SC + n*64 + it + 1], red[0]+red[1]+red[2]+red[3]);
}

// ---------------------------------------------------------------------------
extern "C" void kernel_launch(void* const* d_in, const int* in_sizes, int n_in,
                              void* d_out, int out_size, void* d_ws, size_t ws_size,
                              hipStream_t stream) {
  (void)in_sizes; (void)n_in; (void)out_size; (void)ws_size;
  const float* x    = (const float*)d_in[0];
  const float* dict = (const float*)d_in[1];
  const float* y    = (const float*)d_in[2];
  const float* ax   = (const float*)d_in[3];
  const float* ad   = (const float*)d_in[4];
  const float* regp = (const float*)d_in[5];
  float* out = (float*)d_out;
  float* ws  = (float*)d_ws;   // needs ~6.8 MB

  dim3 b256(256);
  k_sinv<<<dim3(33,4), b256, 0, stream>>>(dict, ax, ws);
  k_e<<<dim3(64,4), b256, 0, stream>>>(x, dict, y, ws);
  k_fft_rows<<<dim3(33,4), b256, 0, stream>>>(ws);
  k_fft_cols<<<dim3(33,4), b256, 0, stream>>>(ws);
  k_ifft_cols<<<dim3(33,4), b256, 0, stream>>>(ws);
  k_ifft_rows<<<dim3(64,4), b256, 0, stream>>>(ws);
  k_xnew<<<dim3(64,4), b256, 0, stream>>>(x, dict, ws, out);
  k_corr<<<dim3(1056,4), b256, 0, stream>>>(out, ws);
  k_pm<<<dim3(64,4), b256, 0, stream>>>(out, y, dict, ad, regp, ws);

  // ---- CG solve (R-direct matvec, fused p/Ap recurrence) ----
  k_cg_zero<<<dim3(1), b256, 0, stream>>>(ws);
  k_cg_init<<<dim3(7,4), b256, 0, stream>>>(ws);
  k_cg_first<<<dim3(64,4), b256, 0, stream>>>(ws, ad, regp);
  for (int it = 0; it < NIT; ++it) {
    k_cg_upd<<<dim3(7,4), b256, 0, stream>>>(ws, it, (it == NIT-1) ? 1 : 0, out);
    if (it < NIT-1)
      k_cg_step<<<dim3(64,4), b256, 0, stream>>>(ws, it, ad, regp);
  }
}

// Round 7
// 890.937 us; speedup vs baseline: 1.6825x; 1.0313x over previous
//
#include <hip/hip_runtime.h>
#include <math.h>

#define PI_F 3.14159265358979323846f

#define NS   4
#define CIN  64
#define HH   128
#define WW   128
#define KXN  65          // rfft last-axis size
#define NPIX (HH*WW)
#define MMAT 1600        // CIN*5*5
#define NIT  8           // CG iterations (rate ~0.32/iter; floor is fp32 front-end)

// float offsets in workspace (~6.8 MB)
#define OFF_SINV 0
#define OFF_E    33280
#define OFF_ER   98816
#define OFF_EW   165376   // (unused now, kept for layout clarity)
#define OFF_VR   231936
#define OFF_WB   298496
#define OFF_R    364032   // 4*64*64*81 = 1,327,104 floats
#define OFF_PM   1691136
// CG state reuses the (dead-by-then) front-end scratch at offset 0:
#define OFF_DV   0
#define OFF_RV   6400
#define OFF_PV   12800
#define OFF_AP   19200
// scalar partial-sum slots (no atomics, no pre-zero; every slot written before read)
#define OFF_RR0P 25600            // [n*64 + i]           rr0 partials (from k_pm)
#define OFF_PAPP 25856            // [it*256 + n*64 + j]  pAp partials, it 0..8
#define OFF_RRP  28160            // [it*32 + n*8 + blk]  rr[it+1] partials, it 0..7

#define WRED(x) { (x)+=__shfl_down((x),32); (x)+=__shfl_down((x),16); (x)+=__shfl_down((x),8); \
                  (x)+=__shfl_down((x),4);  (x)+=__shfl_down((x),2);  (x)+=__shfl_down((x),1); }

// ---------------------------------------------------------------------------
// Sinv[n,ky,kx] = 1 / (sum_c |D_c(ky,kx)|^2 + alpha_x/64); D from 5x5 psf DFT
// ---------------------------------------------------------------------------
__global__ __launch_bounds__(256) void k_sinv(const float* __restrict__ dict,
                                              const float* __restrict__ alpha_x,
                                              float* __restrict__ ws) {
  int idx = blockIdx.x * 256 + threadIdx.x;
  int n = blockIdx.y;
  if (idx >= HH * KXN) return;
  int ky = idx / KXN, kx = idx % KXN;
  float tr[25], ti[25];
  {
    float eyr[5], eyi[5], exr[5], exi[5];
#pragma unroll
    for (int a = 0; a < 5; ++a) {
      float s, c;
      sincosf(-2.0f * PI_F * (float)(ky * (a - 2)) / 128.0f, &s, &c);
      eyr[a] = c; eyi[a] = s;
      sincosf(-2.0f * PI_F * (float)(kx * (a - 2)) / 128.0f, &s, &c);
      exr[a] = c; exi[a] = s;
    }
#pragma unroll
    for (int a = 0; a < 5; ++a)
#pragma unroll
      for (int b = 0; b < 5; ++b) {
        tr[a*5+b] = eyr[a]*exr[b] - eyi[a]*exi[b];
        ti[a*5+b] = eyr[a]*exi[b] + eyi[a]*exr[b];
      }
  }
  const float* dn = dict + n * CIN * 25;
  float S = 0.0f;
  for (int c = 0; c < CIN; ++c) {
    const float* p = dn + c * 25;
    float Dr = 0.0f, Di = 0.0f;
#pragma unroll
    for (int t = 0; t < 25; ++t) { Dr += p[t]*tr[t]; Di += p[t]*ti[t]; }
    S += Dr*Dr + Di*Di;
  }
  float a = alpha_x[n] * (1.0f/64.0f);
  ws[OFF_SINV + (n*HH + ky)*KXN + kx] = 1.0f / (S + a);
}

// ---------------------------------------------------------------------------
// e[n,p] = y[n,p] - sum_c sum_{a,b} psf[n,c,a,b] * x[..circular..]
// ---------------------------------------------------------------------------
__global__ __launch_bounds__(256) void k_e(const float* __restrict__ x,
                                           const float* __restrict__ dict,
                                           const float* __restrict__ y,
                                           float* __restrict__ ws) {
  __shared__ float psf_s[CIN*25];
  __shared__ float xt[20*20];
  int n = blockIdx.y, tile = blockIdx.x, tid = threadIdx.x;
  int h0 = (tile >> 3) * 16, w0 = (tile & 7) * 16;
  for (int i = tid; i < CIN*25; i += 256) psf_s[i] = dict[n*CIN*25 + i];
  int py = tid >> 4, px = tid & 15;
  float acc = 0.0f;
  for (int c = 0; c < CIN; ++c) {
    __syncthreads();
    for (int i = tid; i < 400; i += 256) {
      int r = i / 20, cc = i % 20;
      int gh = (h0 + r - 2) & 127, gw = (w0 + cc - 2) & 127;
      xt[i] = x[((n*CIN + c)*HH + gh)*WW + gw];
    }
    __syncthreads();
    const float* pp = psf_s + c*25;
#pragma unroll
    for (int a = 0; a < 5; ++a)
#pragma unroll
      for (int b = 0; b < 5; ++b)
        acc += pp[a*5+b] * xt[(py+a)*20 + (px+b)];
  }
  int h = h0+py, w = w0+px;
  ws[OFF_E + (n*HH + h)*WW + w] = y[(n*HH + h)*WW + w] - acc;
}

// ---------------------------------------------------------------------------
// row DFT: ER[h,kx] = sum_w E[h,w] cis(-2pi w kx/128)
// ---------------------------------------------------------------------------
__global__ __launch_bounds__(256) void k_fft_rows(float* __restrict__ ws) {
  __shared__ float twr[128], twi[128];
  int tid = threadIdx.x;
  if (tid < 128) { float s, c; sincosf(-2.0f*PI_F*(float)tid/128.0f, &s, &c); twr[tid]=c; twi[tid]=s; }
  __syncthreads();
  int idx = blockIdx.x*256 + tid, n = blockIdx.y;
  if (idx >= HH*KXN) return;
  int h = idx / KXN, k = idx % KXN;
  const float* row = ws + OFF_E + (n*HH + h)*WW;
  float sr = 0, si = 0;
  for (int w = 0; w < 128; ++w) {
    int t = (w*k) & 127;
    float v = row[w];
    sr += v*twr[t]; si += v*twi[t];
  }
  float* o = ws + OFF_ER + ((n*HH + h)*KXN + k)*2;
  o[0] = sr; o[1] = si;
}

// ---------------------------------------------------------------------------
// column pipeline: forward column DFT, * Sinv, inverse column DFT — one block
// per (kx, n); EW column never leaves LDS.
// ---------------------------------------------------------------------------
__global__ __launch_bounds__(128) void k_fft_colpipe(float* __restrict__ ws) {
  __shared__ float twr[128], twi[128];
  __shared__ float ecr[128], eci[128];   // ER column
  __shared__ float ewr[128], ewi[128];   // EW column
  int tid = threadIdx.x;
  int kx = blockIdx.x, n = blockIdx.y;
  { float s, c; sincosf(-2.0f*PI_F*(float)tid/128.0f, &s, &c); twr[tid]=c; twi[tid]=s; }
  const float* Er = ws + OFF_ER + (size_t)n*HH*KXN*2;
  ecr[tid] = Er[(tid*KXN + kx)*2];
  eci[tid] = Er[(tid*KXN + kx)*2 + 1];
  __syncthreads();
  // forward: ky = tid
  {
    int ky = tid;
    float sr = 0, si = 0;
    for (int h = 0; h < 128; ++h) {
      int t = (h*ky) & 127;
      float ar = ecr[h], ai = eci[h];
      sr += ar*twr[t] - ai*twi[t];
      si += ar*twi[t] + ai*twr[t];
    }
    float sv = ws[OFF_SINV + (n*HH + ky)*KXN + kx];
    ewr[ky] = sr*sv; ewi[ky] = si*sv;
  }
  __syncthreads();
  // inverse: h = tid, multiply by cis(+theta) = (twr, -twi)
  {
    int h = tid;
    float sr = 0, si = 0;
    for (int ky = 0; ky < 128; ++ky) {
      int t = (h*ky) & 127;
      float ar = ewr[ky], ai = ewi[ky];
      sr += ar*twr[t] + ai*twi[t];
      si += ai*twr[t] - ar*twi[t];
    }
    float* o = ws + OFF_VR + ((n*HH + h)*KXN + kx)*2;
    o[0] = sr; o[1] = si;
  }
}

__global__ __launch_bounds__(256) void k_ifft_rows(float* __restrict__ ws) {
  __shared__ float twr[128], twi[128];
  int tid = threadIdx.x;
  if (tid < 128) { float s, c; sincosf(-2.0f*PI_F*(float)tid/128.0f, &s, &c); twr[tid]=c; twi[tid]=s; }
  __syncthreads();
  int idx = blockIdx.x*256 + tid, n = blockIdx.y;
  int h = idx >> 7, w = idx & 127;
  const float* Vr = ws + OFF_VR + (size_t)n*HH*KXN*2;
  float s = 0.0f;
  for (int kx = 0; kx <= 64; ++kx) {
    int t = (w*kx) & 127;
    float ar = Vr[(h*KXN + kx)*2], ai = Vr[(h*KXN + kx)*2 + 1];
    float re = ar*twr[t] + ai*twi[t];
    s += (kx == 0 || kx == 64) ? re : 2.0f*re;
  }
  ws[OFF_WB + (n*HH + h)*WW + w] = s * (1.0f/16384.0f);
}

// ---------------------------------------------------------------------------
// x_new[n,c,p] = x[n,c,p] + sum_{a,b} psf[n,c,a,b]*wbuf[circ]
// ---------------------------------------------------------------------------
__global__ __launch_bounds__(256) void k_xnew(const float* __restrict__ x,
                                              const float* __restrict__ dict,
                                              const float* __restrict__ ws,
                                              float* __restrict__ out) {
  __shared__ float psf_s[CIN*25];
  __shared__ float wt[20*20];
  int n = blockIdx.y, tile = blockIdx.x, tid = threadIdx.x;
  int h0 = (tile >> 3) * 16, w0 = (tile & 7) * 16;
  for (int i = tid; i < CIN*25; i += 256) psf_s[i] = dict[n*CIN*25 + i];
  for (int i = tid; i < 400; i += 256) {
    int r = i / 20, cc = i % 20;
    int gh = (h0 + r - 2) & 127, gw = (w0 + cc - 2) & 127;
    wt[i] = ws[OFF_WB + (n*HH + gh)*WW + gw];
  }
  __syncthreads();
  int py = tid >> 4, px = tid & 15;
  int h = h0+py, w = w0+px;
  for (int c = 0; c < CIN; ++c) {
    float acc = 0.0f;
    const float* pp = psf_s + c*25;
#pragma unroll
    for (int a = 0; a < 5; ++a)
#pragma unroll
      for (int b = 0; b < 5; ++b)
        acc += pp[a*5+b] * wt[(py + 4 - a)*20 + (px + 4 - b)];
    int gi = ((n*CIN + c)*HH + h)*WW + w;
    out[gi] = x[gi] + acc;
  }
}

// ---------------------------------------------------------------------------
// R[n,i,j,u,v] = sum_{h,w} xnew_i[h+u-4, w+v-4] * xnew_j[h,w]  (zero-pad)
// v7: J=3 channels per block (window reuse x3), lane-consecutive 4-wide
// windows (conflict-clean), u-split across waves (u in {w,w+4}; u=8 rotating
// duty). acc=81 regs -> ~115 VGPR, no occupancy floor (no spills).
// ---------------------------------------------------------------------------
__global__ __launch_bounds__(256) void k_corr(const float* __restrict__ xn,
                                              float* __restrict__ ws) {
  __shared__ float xi_s[40*136];
  __shared__ float red8[4][3][9];
  int n = blockIdx.y, p = blockIdx.x, tid = threadIdx.x;
  // decode p -> (ii, jb), jb in 0..ceil((ii+1)/3)-1
  int ii = 0, cum = 0;
  while (cum + (ii+3)/3 <= p) { cum += (ii+3)/3; ++ii; }
  int jb = p - cum;
  int jc[3] = {3*jb, 3*jb+1, 3*jb+2};
  int jok[3] = {jc[0] <= ii, jc[1] <= ii, jc[2] <= ii};
  int jr[3]  = {jc[0], jc[1] <= 63 ? jc[1] : 63, jc[2] <= 63 ? jc[2] : 63};
  const float* Xi  = xn + (size_t)(n*CIN + ii)*NPIX;
  const float* Xj0 = xn + (size_t)(n*CIN + jr[0])*NPIX;
  const float* Xj1 = xn + (size_t)(n*CIN + jr[1])*NPIX;
  const float* Xj2 = xn + (size_t)(n*CIN + jr[2])*NPIX;
  int wv = tid >> 6, lane = tid & 63;
  int l16 = lane & 15, rg = lane >> 4;   // 16 col-chunks x 4 rows per wave
  const int uA = wv, uB = wv + 4;
  float accA[3][9], accB[3][9], accC[3][9];
#pragma unroll
  for (int j = 0; j < 3; ++j)
#pragma unroll
    for (int v = 0; v < 9; ++v) { accA[j][v]=0.0f; accB[j][v]=0.0f; accC[j][v]=0.0f; }

  for (int q = 0; q < 4; ++q) {
    __syncthreads();
    for (int t = tid; t < 40*136; t += 256) {
      int r = t / 136, c = t % 136;
      int gh = q*32 - 4 + r, gw = c - 4;
      float v = 0.0f;
      if (gh >= 0 && gh < 128 && gw >= 0 && gw < 128) v = Xi[gh*128 + gw];
      xi_s[t] = v;
    }
    __syncthreads();
#pragma unroll
    for (int ch = 0; ch < 2; ++ch) {
      int wbase = ch*64 + (l16 << 2);
      for (int it = 0; it < 8; ++it) {
        int hl = (it << 2) + rg;
        int grow = (q*32 + hl)*128 + wbase;
        const float4 x0 = *reinterpret_cast<const float4*>(Xj0 + grow);
        const float4 x1 = *reinterpret_cast<const float4*>(Xj1 + grow);
        const float4 x2 = *reinterpret_cast<const float4*>(Xj2 + grow);
        float xj[3][4] = {{x0.x,x0.y,x0.z,x0.w},{x1.x,x1.y,x1.z,x1.w},{x2.x,x2.y,x2.z,x2.w}};
        {
          const float* rp = &xi_s[(hl + uA)*136 + wbase];
          const float4 a0 = *reinterpret_cast<const float4*>(rp);
          const float4 a1 = *reinterpret_cast<const float4*>(rp + 4);
          const float4 a2 = *reinterpret_cast<const float4*>(rp + 8);
          float xw[12] = {a0.x,a0.y,a0.z,a0.w, a1.x,a1.y,a1.z,a1.w, a2.x,a2.y,a2.z,a2.w};
#pragma unroll
          for (int v = 0; v < 9; ++v)
#pragma unroll
            for (int k = 0; k < 4; ++k) {
              accA[0][v] += xw[v+k]*xj[0][k];
              accA[1][v] += xw[v+k]*xj[1][k];
              accA[2][v] += xw[v+k]*xj[2][k];
            }
        }
        {
          const float* rp = &xi_s[(hl + uB)*136 + wbase];
          const float4 a0 = *reinterpret_cast<const float4*>(rp);
          const float4 a1 = *reinterpret_cast<const float4*>(rp + 4);
          const float4 a2 = *reinterpret_cast<const float4*>(rp + 8);
          float xw[12] = {a0.x,a0.y,a0.z,a0.w, a1.x,a1.y,a1.z,a1.w, a2.x,a2.y,a2.z,a2.w};
#pragma unroll
          for (int v = 0; v < 9; ++v)
#pragma unroll
            for (int k = 0; k < 4; ++k) {
              accB[0][v] += xw[v+k]*xj[0][k];
              accB[1][v] += xw[v+k]*xj[1][k];
              accB[2][v] += xw[v+k]*xj[2][k];
            }
        }
        if ((it >> 1) == wv) {               // u=8, rotating duty
          const float* rp = &xi_s[(hl + 8)*136 + wbase];
          const float4 a0 = *reinterpret_cast<const float4*>(rp);
          const float4 a1 = *reinterpret_cast<const float4*>(rp + 4);
          const float4 a2 = *reinterpret_cast<const float4*>(rp + 8);
          float xw[12] = {a0.x,a0.y,a0.z,a0.w, a1.x,a1.y,a1.z,a1.w, a2.x,a2.y,a2.z,a2.w};
#pragma unroll
          for (int v = 0; v < 9; ++v)
#pragma unroll
            for (int k = 0; k < 4; ++k) {
              accC[0][v] += xw[v+k]*xj[0][k];
              accC[1][v] += xw[v+k]*xj[1][k];
              accC[2][v] += xw[v+k]*xj[2][k];
            }
        }
      }
    }
  }
#pragma unroll
  for (int v = 0; v < 9; ++v) {
    WRED(accA[0][v]); WRED(accA[1][v]); WRED(accA[2][v]);
    WRED(accB[0][v]); WRED(accB[1][v]); WRED(accB[2][v]);
    WRED(accC[0][v]); WRED(accC[1][v]); WRED(accC[2][v]);
  }
  float* Rp = ws + OFF_R;
  if (lane == 0) {
#pragma unroll
    for (int j = 0; j < 3; ++j) {
#pragma unroll
      for (int v = 0; v < 9; ++v) red8[wv][j][v] = accC[j][v];
      if (jok[j]) {
        size_t b  = (((size_t)n*CIN + ii)*CIN + jr[j])*81;
        size_t bT = (((size_t)n*CIN + jr[j])*CIN + ii)*81;
#pragma unroll
        for (int v = 0; v < 9; ++v) {
          int uv = uA*9 + v;
          Rp[b + uv] = accA[j][v];
          Rp[bT + 80 - uv] = accA[j][v];
        }
#pragma unroll
        for (int v = 0; v < 9; ++v) {
          int uv = uB*9 + v;
          Rp[b + uv] = accB[j][v];
          Rp[bT + 80 - uv] = accB[j][v];
        }
      }
    }
  }
  __syncthreads();
  {
    int g = tid >> 4, v = tid & 15;
    if (g < 3 && v < 9 && jok[g]) {
      float s = red8[0][g][v] + red8[1][g][v] + red8[2][g][v] + red8[3][g][v];
      size_t b  = (((size_t)n*CIN + ii)*CIN + jr[g])*81;
      size_t bT = (((size_t)n*CIN + jr[g])*CIN + ii)*81;
      Rp[b + 72 + v] = s;
      Rp[bT + 8 - v] = s;
    }
  }
}

// ---------------------------------------------------------------------------
// Pm -> writes CG initial state directly: RV = PV = Pm; rr0 partials per i.
// ---------------------------------------------------------------------------
__global__ __launch_bounds__(256) void k_pm(const float* __restrict__ xn,
                                            const float* __restrict__ y,
                                            const float* __restrict__ dict,
                                            const float* __restrict__ alpha_d,
                                            const float* __restrict__ regp,
                                            float* __restrict__ ws) {
  __shared__ float xt[20*20];
  __shared__ float red_s[4][25];
  int n = blockIdx.y, i = blockIdx.x, tid = threadIdx.x;
  int py = tid >> 4, px = tid & 15;
  float acc[25];
#pragma unroll
  for (int t = 0; t < 25; ++t) acc[t] = 0.0f;
  const float* Xi = xn + (size_t)(n*CIN + i)*NPIX;
  for (int tile = 0; tile < 64; ++tile) {
    int h0 = (tile >> 3)*16, w0 = (tile & 7)*16;
    __syncthreads();
    for (int t = tid; t < 400; t += 256) {
      int r = t / 20, cc = t % 20;
      int gh = h0 + r - 2, gw = w0 + cc - 2;
      float v = 0.0f;
      if (gh >= 0 && gh < 128 && gw >= 0 && gw < 128) v = Xi[gh*128 + gw];
      xt[t] = v;
    }
    __syncthreads();
    float yv = y[(n*HH + h0 + py)*WW + w0 + px];
#pragma unroll
    for (int u = 0; u < 5; ++u)
#pragma unroll
      for (int v = 0; v < 5; ++v)
        acc[u*5+v] += xt[(py+u)*20 + (px+v)] * yv;
  }
  int lane = tid & 63, wv = tid >> 6;
#pragma unroll
  for (int t = 0; t < 25; ++t) {
    float v = acc[t];
    WRED(v);
    if (lane == 0) red_s[wv][t] = v;
  }
  __syncthreads();
  float sq = 0.0f;
  if (tid < 25) {
    float s = red_s[0][tid] + red_s[1][tid] + red_s[2][tid] + red_s[3][tid];
    float ad = alpha_d[n] * 16384.0f * regp[0] * (1.0f/1600.0f);
    float val = s + ad * dict[(n*CIN + i)*25 + tid];
    int idx = n*MMAT + i*25 + tid;
    ws[OFF_RV + idx] = val;
    ws[OFF_PV + idx] = val;
    sq = val*val;
  }
  if (tid < 64) {
    WRED(sq);
    if (tid == 0) ws[OFF_RR0P + n*64 + i] = sq;
  }
}

// ---------------------------------------------------------------------------
// CG on R directly. (A v)[(j,a,c)] = sum_{i,b,d} R[n,i,j,4+b-a,4+d-c] v[(i,b,d)]
//                                    + reg*v
// ---------------------------------------------------------------------------
// Ap0 = Q p0; pAp0 partial per j (no atomics)
__global__ __launch_bounds__(256) void k_cg_first(float* __restrict__ ws,
                                                  const float* __restrict__ alpha_d,
                                                  const float* __restrict__ regp) {
  __shared__ float vv[MMAT];
  __shared__ float part[25][66];
  int n = blockIdx.y, j = blockIdx.x, tid = threadIdx.x;
  for (int t = tid; t < MMAT; t += 256) vv[t] = ws[OFF_PV + n*MMAT + t];
  __syncthreads();
  int i = tid & 63, qq = tid >> 6;
  const float* Rij = ws + OFF_R + (((size_t)n*CIN + i)*CIN + j)*81;
  const float* vi = &vv[i*25];
#pragma unroll
  for (int s6 = 0; s6 < 7; ++s6) {
    int ac = qq + 4*s6;
    if (ac < 25) {
      int a = ac/5, c = ac%5;
      float s = 0.0f;
#pragma unroll
      for (int b = 0; b < 5; ++b)
#pragma unroll
        for (int d = 0; d < 5; ++d)
          s += Rij[(4+b-a)*9 + (4+d-c)] * vi[b*5+d];
      part[ac][i] = s;
    }
  }
  __syncthreads();
  float contrib = 0.0f;
  if (tid < 25) {
    float s = 0.0f;
    for (int t = 0; t < 64; ++t) s += part[tid][t];
    float reg = alpha_d[n] * 16384.0f * regp[0] * (1.0f/1600.0f);
    s += reg * vv[j*25 + tid];
    ws[OFF_AP + n*MMAT + j*25 + tid] = s;
    contrib = s * vv[j*25 + tid];
  }
  if (tid < 64) {
    WRED(contrib);
    if (tid == 0) ws[OFF_PAPP + 0*256 + n*64 + j] = contrib;
  }
}

// p' = r + beta p; Ap' = A r + beta Ap; pAp[it+1] partial per j
__global__ __launch_bounds__(256) void k_cg_step(float* __restrict__ ws, int it,
                                                 const float* __restrict__ alpha_d,
                                                 const float* __restrict__ regp) {
  __shared__ float vv[MMAT];   // r
  __shared__ float part[25][66];
  int n = blockIdx.y, j = blockIdx.x, tid = threadIdx.x;
  for (int t = tid; t < MMAT; t += 256) vv[t] = ws[OFF_RV + n*MMAT + t];
  __syncthreads();
  int i = tid & 63, qq = tid >> 6;
  const float* Rij = ws + OFF_R + (((size_t)n*CIN + i)*CIN + j)*81;
  const float* vi = &vv[i*25];
#pragma unroll
  for (int s6 = 0; s6 < 7; ++s6) {
    int ac = qq + 4*s6;
    if (ac < 25) {
      int a = ac/5, c = ac%5;
      float s = 0.0f;
#pragma unroll
      for (int b = 0; b < 5; ++b)
#pragma unroll
        for (int d = 0; d < 5; ++d)
          s += Rij[(4+b-a)*9 + (4+d-c)] * vi[b*5+d];
      part[ac][i] = s;
    }
  }
  __syncthreads();
  float contrib = 0.0f;
  if (tid < 25) {
    // rr[it+1] (from upd(it)) and rr[it]
    float rr_n = 0.0f, rr_d = 0.0f;
    for (int t = 0; t < 7; ++t) rr_n += ws[OFF_RRP + it*32 + n*8 + t];
    if (it == 0) { for (int t = 0; t < 64; ++t) rr_d += ws[OFF_RR0P + n*64 + t]; }
    else         { for (int t = 0; t < 7;  ++t) rr_d += ws[OFF_RRP + (it-1)*32 + n*8 + t]; }
    float beta = rr_n / (rr_d + 1e-30f);
    float s = 0.0f;
    for (int t = 0; t < 64; ++t) s += part[tid][t];
    float reg = alpha_d[n] * 16384.0f * regp[0] * (1.0f/1600.0f);
    s += reg * vv[j*25 + tid];                 // s = (Q r)[j*25+tid]
    int idx = n*MMAT + j*25 + tid;
    float pn  = vv[j*25 + tid] + beta * ws[OFF_PV + idx];
    float apn = s + beta * ws[OFF_AP + idx];
    ws[OFF_PV + idx] = pn;
    ws[OFF_AP + idx] = apn;
    contrib = pn * apn;
  }
  if (tid < 64) {
    WRED(contrib);
    if (tid == 0) ws[OFF_PAPP + (it+1)*256 + n*64 + j] = contrib;
  }
}

// alpha = rr[it]/pAp[it]; d += alpha p; r -= alpha Ap; rr[it+1] partial per block
__global__ __launch_bounds__(256) void k_cg_upd(float* __restrict__ ws, int it,
                                                int last, float* __restrict__ out) {
  int n = blockIdx.y, i = blockIdx.x*256 + threadIdx.x;
  float rr = 0.0f, pap = 0.0f;
  if (it == 0) { for (int t = 0; t < 64; ++t) rr += ws[OFF_RR0P + n*64 + t]; }
  else         { for (int t = 0; t < 7;  ++t) rr += ws[OFF_RRP + (it-1)*32 + n*8 + t]; }
  for (int t = 0; t < 64; ++t) pap += ws[OFF_PAPP + it*256 + n*64 + t];
  float alpha = rr / (pap + 1e-30f);
  float rn = 0.0f;
  if (i < MMAT) {
    float dprev = (it == 0) ? 0.0f : ws[OFF_DV + n*MMAT + i];
    float dv = dprev + alpha * ws[OFF_PV + n*MMAT + i];
    rn = ws[OFF_RV + n*MMAT + i] - alpha * ws[OFF_AP + n*MMAT + i];
    ws[OFF_DV + n*MMAT + i] = dv;
    ws[OFF_RV + n*MMAT + i] = rn;
    if (last) out[4194304 + n*MMAT + i] = dv;
  }
  float part = rn*rn;
  WRED(part);
  __shared__ float red[4];
  int lane = threadIdx.x & 63, w = threadIdx.x >> 6;
  if (lane == 0) red[w] = part;
  __syncthreads();
  if (threadIdx.x == 0)
    ws[OFF_RRP + it*32 + n*8 + blockIdx.x] = red[0]+red[1]+red[2]+red[3];
}

// ---------------------------------------------------------------------------
extern "C" void kernel_launch(void* const* d_in, const int* in_sizes, int n_in,
                              void* d_out, int out_size, void* d_ws, size_t ws_size,
                              hipStream_t stream) {
  (void)in_sizes; (void)n_in; (void)out_size; (void)ws_size;
  const float* x    = (const float*)d_in[0];
  const float* dict = (const float*)d_in[1];
  const float* y    = (const float*)d_in[2];
  const float* ax   = (const float*)d_in[3];
  const float* ad   = (const float*)d_in[4];
  const float* regp = (const float*)d_in[5];
  float* out = (float*)d_out;
  float* ws  = (float*)d_ws;   // needs ~6.8 MB

  dim3 b256(256);
  k_sinv<<<dim3(33,4), b256, 0, stream>>>(dict, ax, ws);
  k_e<<<dim3(64,4), b256, 0, stream>>>(x, dict, y, ws);
  k_fft_rows<<<dim3(33,4), b256, 0, stream>>>(ws);
  k_fft_colpipe<<<dim3(65,4), dim3(128), 0, stream>>>(ws);
  k_ifft_rows<<<dim3(64,4), b256, 0, stream>>>(ws);
  k_xnew<<<dim3(64,4), b256, 0, stream>>>(x, dict, ws, out);
  k_corr<<<dim3(715,4), b256, 0, stream>>>(out, ws);
  k_pm<<<dim3(64,4), b256, 0, stream>>>(out, y, dict, ad, regp, ws);

  // ---- CG solve (R-direct matvec, fused p/Ap recurrence, no atomics) ----
  k_cg_first<<<dim3(64,4), b256, 0, stream>>>(ws, ad, regp);
  for (int it = 0; it < NIT; ++it) {
    k_cg_upd<<<dim3(7,4), b256, 0, stream>>>(ws, it, (it == NIT-1) ? 1 : 0, out);
    if (it < NIT-1)
      k_cg_step<<<dim3(64,4), b256, 0, stream>>>(ws, it, ad, regp);
  }
}

// Round 8
// 590.917 us; speedup vs baseline: 2.5368x; 1.5077x over previous
//
#include <hip/hip_runtime.h>
#include <hip/hip_bf16.h>
#include <math.h>

#define PI_F 3.14159265358979323846f

#define NS   4
#define CIN  64
#define HH   128
#define WW   128
#define KXN  65          // rfft last-axis size
#define NPIX (HH*WW)
#define MMAT 1600        // CIN*5*5
#define NIT  8           // CG iterations

// float offsets in workspace (budget: 11,937,536 floats = 47.75 MB, proven)
#define OFF_SINV 0
#define OFF_E    33280
#define OFF_ER   98816
#define OFF_VR   231936
#define OFF_WB   298496
#define OFF_R    364032      // 4*64*64*81 = 1,327,104 floats -> ends 1,691,136
#define OFF_RP   1691136    // GEMM partials: 8 sl * 4 n * 42 s * 4096 = 5,505,024 -> ends 7,196,160
#define OFF_XB   7196160    // bf16 padded copies: 2*(4,734,976)+8 ushorts = 18.94 MB
#define XB0C     4734976    // ushorts per copy (4*64*136*136)
// CG state reuses the (dead-by-then) front-end scratch at offset 0:
#define OFF_DV   0
#define OFF_RV   6400
#define OFF_PV   12800
#define OFF_AP   19200
#define OFF_RR0P 25600      // [n*64 + i] rr0 partials (from k_pm)
#define OFF_PAPP 25856      // [it*256 + n*64 + j] pAp partials
#define OFF_RRP  28160      // [it*32 + n*8 + blk] rr partials

#define WRED(x) { (x)+=__shfl_down((x),32); (x)+=__shfl_down((x),16); (x)+=__shfl_down((x),8); \
                  (x)+=__shfl_down((x),4);  (x)+=__shfl_down((x),2);  (x)+=__shfl_down((x),1); }

typedef __attribute__((ext_vector_type(8))) short bf16x8;
typedef __attribute__((ext_vector_type(4))) float f32x4;

// ---------------------------------------------------------------------------
// Sinv[n,ky,kx] = 1 / (sum_c |D_c(ky,kx)|^2 + alpha_x/64)
// ---------------------------------------------------------------------------
__global__ __launch_bounds__(256) void k_sinv(const float* __restrict__ dict,
                                              const float* __restrict__ alpha_x,
                                              float* __restrict__ ws) {
  int idx = blockIdx.x * 256 + threadIdx.x;
  int n = blockIdx.y;
  if (idx >= HH * KXN) return;
  int ky = idx / KXN, kx = idx % KXN;
  float tr[25], ti[25];
  {
    float eyr[5], eyi[5], exr[5], exi[5];
#pragma unroll
    for (int a = 0; a < 5; ++a) {
      float s, c;
      sincosf(-2.0f * PI_F * (float)(ky * (a - 2)) / 128.0f, &s, &c);
      eyr[a] = c; eyi[a] = s;
      sincosf(-2.0f * PI_F * (float)(kx * (a - 2)) / 128.0f, &s, &c);
      exr[a] = c; exi[a] = s;
    }
#pragma unroll
    for (int a = 0; a < 5; ++a)
#pragma unroll
      for (int b = 0; b < 5; ++b) {
        tr[a*5+b] = eyr[a]*exr[b] - eyi[a]*exi[b];
        ti[a*5+b] = eyr[a]*exi[b] + eyi[a]*exr[b];
      }
  }
  const float* dn = dict + n * CIN * 25;
  float S = 0.0f;
  for (int c = 0; c < CIN; ++c) {
    const float* p = dn + c * 25;
    float Dr = 0.0f, Di = 0.0f;
#pragma unroll
    for (int t = 0; t < 25; ++t) { Dr += p[t]*tr[t]; Di += p[t]*ti[t]; }
    S += Dr*Dr + Di*Di;
  }
  float a = alpha_x[n] * (1.0f/64.0f);
  ws[OFF_SINV + (n*HH + ky)*KXN + kx] = 1.0f / (S + a);
}

// ---------------------------------------------------------------------------
// e[n,p] = y[n,p] - sum_c sum_{a,b} psf[n,c,a,b] * x[..circular..]
// ---------------------------------------------------------------------------
__global__ __launch_bounds__(256) void k_e(const float* __restrict__ x,
                                           const float* __restrict__ dict,
                                           const float* __restrict__ y,
                                           float* __restrict__ ws) {
  __shared__ float psf_s[CIN*25];
  __shared__ float xt[20*20];
  int n = blockIdx.y, tile = blockIdx.x, tid = threadIdx.x;
  int h0 = (tile >> 3) * 16, w0 = (tile & 7) * 16;
  for (int i = tid; i < CIN*25; i += 256) psf_s[i] = dict[n*CIN*25 + i];
  int py = tid >> 4, px = tid & 15;
  float acc = 0.0f;
  for (int c = 0; c < CIN; ++c) {
    __syncthreads();
    for (int i = tid; i < 400; i += 256) {
      int r = i / 20, cc = i % 20;
      int gh = (h0 + r - 2) & 127, gw = (w0 + cc - 2) & 127;
      xt[i] = x[((n*CIN + c)*HH + gh)*WW + gw];
    }
    __syncthreads();
    const float* pp = psf_s + c*25;
#pragma unroll
    for (int a = 0; a < 5; ++a)
#pragma unroll
      for (int b = 0; b < 5; ++b)
        acc += pp[a*5+b] * xt[(py+a)*20 + (px+b)];
  }
  int h = h0+py, w = w0+px;
  ws[OFF_E + (n*HH + h)*WW + w] = y[(n*HH + h)*WW + w] - acc;
}

// ---------------------------------------------------------------------------
// row DFT
// ---------------------------------------------------------------------------
__global__ __launch_bounds__(256) void k_fft_rows(float* __restrict__ ws) {
  __shared__ float twr[128], twi[128];
  int tid = threadIdx.x;
  if (tid < 128) { float s, c; sincosf(-2.0f*PI_F*(float)tid/128.0f, &s, &c); twr[tid]=c; twi[tid]=s; }
  __syncthreads();
  int idx = blockIdx.x*256 + tid, n = blockIdx.y;
  if (idx >= HH*KXN) return;
  int h = idx / KXN, k = idx % KXN;
  const float* row = ws + OFF_E + (n*HH + h)*WW;
  float sr = 0, si = 0;
  for (int w = 0; w < 128; ++w) {
    int t = (w*k) & 127;
    float v = row[w];
    sr += v*twr[t]; si += v*twi[t];
  }
  float* o = ws + OFF_ER + ((n*HH + h)*KXN + k)*2;
  o[0] = sr; o[1] = si;
}

// ---------------------------------------------------------------------------
// column pipeline: fwd DFT * Sinv, inverse DFT — column stays in LDS
// ---------------------------------------------------------------------------
__global__ __launch_bounds__(128) void k_fft_colpipe(float* __restrict__ ws) {
  __shared__ float twr[128], twi[128];
  __shared__ float ecr[128], eci[128];
  __shared__ float ewr[128], ewi[128];
  int tid = threadIdx.x;
  int kx = blockIdx.x, n = blockIdx.y;
  { float s, c; sincosf(-2.0f*PI_F*(float)tid/128.0f, &s, &c); twr[tid]=c; twi[tid]=s; }
  const float* Er = ws + OFF_ER + (size_t)n*HH*KXN*2;
  ecr[tid] = Er[(tid*KXN + kx)*2];
  eci[tid] = Er[(tid*KXN + kx)*2 + 1];
  __syncthreads();
  {
    int ky = tid;
    float sr = 0, si = 0;
    for (int h = 0; h < 128; ++h) {
      int t = (h*ky) & 127;
      float ar = ecr[h], ai = eci[h];
      sr += ar*twr[t] - ai*twi[t];
      si += ar*twi[t] + ai*twr[t];
    }
    float sv = ws[OFF_SINV + (n*HH + ky)*KXN + kx];
    ewr[ky] = sr*sv; ewi[ky] = si*sv;
  }
  __syncthreads();
  {
    int h = tid;
    float sr = 0, si = 0;
    for (int ky = 0; ky < 128; ++ky) {
      int t = (h*ky) & 127;
      float ar = ewr[ky], ai = ewi[ky];
      sr += ar*twr[t] + ai*twi[t];
      si += ai*twr[t] - ar*twi[t];
    }
    float* o = ws + OFF_VR + ((n*HH + h)*KXN + kx)*2;
    o[0] = sr; o[1] = si;
  }
}

__global__ __launch_bounds__(256) void k_ifft_rows(float* __restrict__ ws) {
  __shared__ float twr[128], twi[128];
  int tid = threadIdx.x;
  if (tid < 128) { float s, c; sincosf(-2.0f*PI_F*(float)tid/128.0f, &s, &c); twr[tid]=c; twi[tid]=s; }
  __syncthreads();
  int idx = blockIdx.x*256 + tid, n = blockIdx.y;
  int h = idx >> 7, w = idx & 127;
  const float* Vr = ws + OFF_VR + (size_t)n*HH*KXN*2;
  float s = 0.0f;
  for (int kx = 0; kx <= 64; ++kx) {
    int t = (w*kx) & 127;
    float ar = Vr[(h*KXN + kx)*2], ai = Vr[(h*KXN + kx)*2 + 1];
    float re = ar*twr[t] + ai*twi[t];
    s += (kx == 0 || kx == 64) ? re : 2.0f*re;
  }
  ws[OFF_WB + (n*HH + h)*WW + w] = s * (1.0f/16384.0f);
}

// ---------------------------------------------------------------------------
// x_new = x + psf (x) wbuf (circular correlate-back)
// ---------------------------------------------------------------------------
__global__ __launch_bounds__(256) void k_xnew(const float* __restrict__ x,
                                              const float* __restrict__ dict,
                                              const float* __restrict__ ws,
                                              float* __restrict__ out) {
  __shared__ float psf_s[CIN*25];
  __shared__ float wt[20*20];
  int n = blockIdx.y, tile = blockIdx.x, tid = threadIdx.x;
  int h0 = (tile >> 3) * 16, w0 = (tile & 7) * 16;
  for (int i = tid; i < CIN*25; i += 256) psf_s[i] = dict[n*CIN*25 + i];
  for (int i = tid; i < 400; i += 256) {
    int r = i / 20, cc = i % 20;
    int gh = (h0 + r - 2) & 127, gw = (w0 + cc - 2) & 127;
    wt[i] = ws[OFF_WB + (n*HH + gh)*WW + gw];
  }
  __syncthreads();
  int py = tid >> 4, px = tid & 15;
  int h = h0+py, w = w0+px;
  for (int c = 0; c < CIN; ++c) {
    float acc = 0.0f;
    const float* pp = psf_s + c*25;
#pragma unroll
    for (int a = 0; a < 5; ++a)
#pragma unroll
      for (int b = 0; b < 5; ++b)
        acc += pp[a*5+b] * wt[(py + 4 - a)*20 + (px + 4 - b)];
    int gi = ((n*CIN + c)*HH + h)*WW + w;
    out[gi] = x[gi] + acc;
  }
}

// ---------------------------------------------------------------------------
// k_pad: x_new -> zero-padded bf16 image, two copies (copy1 offset by one
// element so odd-v shifted reads are dword-aligned).
// ---------------------------------------------------------------------------
__global__ __launch_bounds__(256) void k_pad(const float* __restrict__ xn,
                                             float* __restrict__ ws) {
  ushort* xb0 = (ushort*)(ws + OFF_XB);
  ushort* xb1 = xb0 + XB0C;
  int ch = blockIdx.y;                  // global channel n*64+c
  int idx = blockIdx.x*256 + threadIdx.x;
  if (ch == 0 && idx == 0) xb1[0] = 0;  // guard slot (element -1)
  if (idx >= 136*136) return;
  int hp = idx / 136, wp = idx % 136;
  float v = 0.0f;
  if (hp >= 4 && hp < 132 && wp >= 4 && wp < 132)
    v = xn[(size_t)ch*NPIX + (hp-4)*128 + (wp-4)];
  __hip_bfloat16 b = __float2bfloat16(v);
  ushort bits = *(ushort*)&b;
  size_t o = (size_t)ch*18496 + idx;
  xb0[o] = bits;
  xb1[o + 1] = bits;
}

// ---------------------------------------------------------------------------
// k_gemm: R_s[i,j] = sum_p Xi[p+delta_s] * Xj[p] via MFMA bf16.
// Shifts s=0..40 <-> uv=s+40 (u=uv/9, v=uv%9). Grid (21 groups x 8 kslices x 4 n).
// Block = 4 waves; wave w owns i-rows 16w..16w+15; 2 shifts, 4 j-tiles.
// Writes per-slice partials (deterministic, no atomics, no pre-zero).
// ---------------------------------------------------------------------------
__device__ inline bf16x8 load_bf8(const ushort* p) {
  const uint* q = (const uint*)p;
  union { uint4 u; bf16x8 s; } cv;
  cv.u.x = q[0]; cv.u.y = q[1]; cv.u.z = q[2]; cv.u.w = q[3];
  return cv.s;
}

__global__ __launch_bounds__(256) void k_gemm(float* __restrict__ ws) {
  const ushort* xb0 = (const ushort*)(ws + OFF_XB);
  const ushort* xb1 = xb0 + XB0C;
  int g = blockIdx.x, sl = blockIdx.y, nn = blockIdx.z;
  int tid = threadIdx.x;
  int wv = tid >> 6, lane = tid & 63;
  int l16 = lane & 15, quad = lane >> 4;
  int i = wv*16 + l16;

  const ushort* baseA[2];
  int svalid[2];
#pragma unroll
  for (int s = 0; s < 2; ++s) {
    int sidx = 2*g + s;
    svalid[s] = (sidx <= 40);
    if (sidx > 40) sidx = 40;
    int uv = sidx + 40;
    int u = uv / 9, v = uv % 9;
    size_t cA = (size_t)(nn*64 + i)*18496 + u*136 + v;
    baseA[s] = (v & 1) ? (xb1 + cA + 1) : (xb0 + cA);
  }
  const ushort* baseB[4];
#pragma unroll
  for (int t = 0; t < 4; ++t)
    baseB[t] = xb0 + (size_t)(nn*64 + t*16 + l16)*18496 + 4*136 + 4;

  f32x4 acc[2][4];
#pragma unroll
  for (int s = 0; s < 2; ++s)
#pragma unroll
    for (int t = 0; t < 4; ++t) acc[s][t] = (f32x4){0.f,0.f,0.f,0.f};

  int k0 = sl*2048 + quad*8;
  for (int kt = 0; kt < 64; ++kt) {
    int p0 = k0 + kt*32;
    int h = p0 >> 7, w0 = p0 & 127;
    int hterm = (h << 7) + (h << 3) + w0;    // h*136 + w0
    bf16x8 b[4];
#pragma unroll
    for (int t = 0; t < 4; ++t) b[t] = load_bf8(baseB[t] + hterm);
    bf16x8 a0 = load_bf8(baseA[0] + hterm);
    bf16x8 a1 = load_bf8(baseA[1] + hterm);
#pragma unroll
    for (int t = 0; t < 4; ++t) {
      acc[0][t] = __builtin_amdgcn_mfma_f32_16x16x32_bf16(a0, b[t], acc[0][t], 0, 0, 0);
      acc[1][t] = __builtin_amdgcn_mfma_f32_16x16x32_bf16(a1, b[t], acc[1][t], 0, 0, 0);
    }
  }

  float* Rp = ws + OFF_RP;
#pragma unroll
  for (int s = 0; s < 2; ++s) {
    if (!svalid[s]) continue;
    size_t base = (((size_t)(sl*4 + nn)*42 + (2*g + s)))*4096;
#pragma unroll
    for (int t = 0; t < 4; ++t) {
#pragma unroll
      for (int r = 0; r < 4; ++r) {
        int iout = wv*16 + quad*4 + r;
        int jout = t*16 + l16;
        Rp[base + iout*64 + jout] = acc[s][t][r];
      }
    }
  }
}

// ---------------------------------------------------------------------------
// k_rmerge: sum 8 k-slices; fill both symmetric halves of R.
// R[n,i,j,uv] ; uv>=40 -> s=uv-40 direct ; uv<40 -> s=40-uv with (i,j) swapped
// ---------------------------------------------------------------------------
__global__ __launch_bounds__(256) void k_rmerge(float* __restrict__ ws) {
  int idx = blockIdx.x*256 + threadIdx.x;    // 1,327,104 total
  int uv = idx % 81;
  int rem = idx / 81;
  int j = rem & 63;
  int i = (rem >> 6) & 63;
  int n = rem >> 12;
  int s, si, sj;
  if (uv >= 40) { s = uv - 40; si = i; sj = j; }
  else          { s = 40 - uv; si = j; sj = i; }
  const float* Rp = ws + OFF_RP;
  float v = 0.0f;
#pragma unroll
  for (int sl = 0; sl < 8; ++sl)
    v += Rp[(((size_t)(sl*4 + n)*42 + s))*4096 + si*64 + sj];
  ws[OFF_R + idx] = v;
}

// ---------------------------------------------------------------------------
// Pm -> CG initial state: RV = PV = Pm; rr0 partials per i.
// ---------------------------------------------------------------------------
__global__ __launch_bounds__(256) void k_pm(const float* __restrict__ xn,
                                            const float* __restrict__ y,
                                            const float* __restrict__ dict,
                                            const float* __restrict__ alpha_d,
                                            const float* __restrict__ regp,
                                            float* __restrict__ ws) {
  __shared__ float xt[20*20];
  __shared__ float red_s[4][25];
  int n = blockIdx.y, i = blockIdx.x, tid = threadIdx.x;
  int py = tid >> 4, px = tid & 15;
  float acc[25];
#pragma unroll
  for (int t = 0; t < 25; ++t) acc[t] = 0.0f;
  const float* Xi = xn + (size_t)(n*CIN + i)*NPIX;
  for (int tile = 0; tile < 64; ++tile) {
    int h0 = (tile >> 3)*16, w0 = (tile & 7)*16;
    __syncthreads();
    for (int t = tid; t < 400; t += 256) {
      int r = t / 20, cc = t % 20;
      int gh = h0 + r - 2, gw = w0 + cc - 2;
      float v = 0.0f;
      if (gh >= 0 && gh < 128 && gw >= 0 && gw < 128) v = Xi[gh*128 + gw];
      xt[t] = v;
    }
    __syncthreads();
    float yv = y[(n*HH + h0 + py)*WW + w0 + px];
#pragma unroll
    for (int u = 0; u < 5; ++u)
#pragma unroll
      for (int v = 0; v < 5; ++v)
        acc[u*5+v] += xt[(py+u)*20 + (px+v)] * yv;
  }
  int lane = tid & 63, wv = tid >> 6;
#pragma unroll
  for (int t = 0; t < 25; ++t) {
    float v = acc[t];
    WRED(v);
    if (lane == 0) red_s[wv][t] = v;
  }
  __syncthreads();
  float sq = 0.0f;
  if (tid < 25) {
    float s = red_s[0][tid] + red_s[1][tid] + red_s[2][tid] + red_s[3][tid];
    float ad = alpha_d[n] * 16384.0f * regp[0] * (1.0f/1600.0f);
    float val = s + ad * dict[(n*CIN + i)*25 + tid];
    int idx = n*MMAT + i*25 + tid;
    ws[OFF_RV + idx] = val;
    ws[OFF_PV + idx] = val;
    sq = val*val;
  }
  if (tid < 64) {
    WRED(sq);
    if (tid == 0) ws[OFF_RR0P + n*64 + i] = sq;
  }
}

// ---------------------------------------------------------------------------
// CG on R directly (no explicit Q).
// ---------------------------------------------------------------------------
__global__ __launch_bounds__(256) void k_cg_first(float* __restrict__ ws,
                                                  const float* __restrict__ alpha_d,
                                                  const float* __restrict__ regp) {
  __shared__ float vv[MMAT];
  __shared__ float part[25][66];
  int n = blockIdx.y, j = blockIdx.x, tid = threadIdx.x;
  for (int t = tid; t < MMAT; t += 256) vv[t] = ws[OFF_PV + n*MMAT + t];
  __syncthreads();
  int i = tid & 63, qq = tid >> 6;
  const float* Rij = ws + OFF_R + (((size_t)n*CIN + i)*CIN + j)*81;
  const float* vi = &vv[i*25];
#pragma unroll
  for (int s6 = 0; s6 < 7; ++s6) {
    int ac = qq + 4*s6;
    if (ac < 25) {
      int a = ac/5, c = ac%5;
      float s = 0.0f;
#pragma unroll
      for (int b = 0; b < 5; ++b)
#pragma unroll
        for (int d = 0; d < 5; ++d)
          s += Rij[(4+b-a)*9 + (4+d-c)] * vi[b*5+d];
      part[ac][i] = s;
    }
  }
  __syncthreads();
  float contrib = 0.0f;
  if (tid < 25) {
    float s = 0.0f;
    for (int t = 0; t < 64; ++t) s += part[tid][t];
    float reg = alpha_d[n] * 16384.0f * regp[0] * (1.0f/1600.0f);
    s += reg * vv[j*25 + tid];
    ws[OFF_AP + n*MMAT + j*25 + tid] = s;
    contrib = s * vv[j*25 + tid];
  }
  if (tid < 64) {
    WRED(contrib);
    if (tid == 0) ws[OFF_PAPP + 0*256 + n*64 + j] = contrib;
  }
}

__global__ __launch_bounds__(256) void k_cg_step(float* __restrict__ ws, int it,
                                                 const float* __restrict__ alpha_d,
                                                 const float* __restrict__ regp) {
  __shared__ float vv[MMAT];
  __shared__ float part[25][66];
  int n = blockIdx.y, j = blockIdx.x, tid = threadIdx.x;
  for (int t = tid; t < MMAT; t += 256) vv[t] = ws[OFF_RV + n*MMAT + t];
  __syncthreads();
  int i = tid & 63, qq = tid >> 6;
  const float* Rij = ws + OFF_R + (((size_t)n*CIN + i)*CIN + j)*81;
  const float* vi = &vv[i*25];
#pragma unroll
  for (int s6 = 0; s6 < 7; ++s6) {
    int ac = qq + 4*s6;
    if (ac < 25) {
      int a = ac/5, c = ac%5;
      float s = 0.0f;
#pragma unroll
      for (int b = 0; b < 5; ++b)
#pragma unroll
        for (int d = 0; d < 5; ++d)
          s += Rij[(4+b-a)*9 + (4+d-c)] * vi[b*5+d];
      part[ac][i] = s;
    }
  }
  __syncthreads();
  float contrib = 0.0f;
  if (tid < 25) {
    float rr_n = 0.0f, rr_d = 0.0f;
    for (int t = 0; t < 7; ++t) rr_n += ws[OFF_RRP + it*32 + n*8 + t];
    if (it == 0) { for (int t = 0; t < 64; ++t) rr_d += ws[OFF_RR0P + n*64 + t]; }
    else         { for (int t = 0; t < 7;  ++t) rr_d += ws[OFF_RRP + (it-1)*32 + n*8 + t]; }
    float beta = rr_n / (rr_d + 1e-30f);
    float s = 0.0f;
    for (int t = 0; t < 64; ++t) s += part[tid][t];
    float reg = alpha_d[n] * 16384.0f * regp[0] * (1.0f/1600.0f);
    s += reg * vv[j*25 + tid];
    int idx = n*MMAT + j*25 + tid;
    float pn  = vv[j*25 + tid] + beta * ws[OFF_PV + idx];
    float apn = s + beta * ws[OFF_AP + idx];
    ws[OFF_PV + idx] = pn;
    ws[OFF_AP + idx] = apn;
    contrib = pn * apn;
  }
  if (tid < 64) {
    WRED(contrib);
    if (tid == 0) ws[OFF_PAPP + (it+1)*256 + n*64 + j] = contrib;
  }
}

__global__ __launch_bounds__(256) void k_cg_upd(float* __restrict__ ws, int it,
                                                int last, float* __restrict__ out) {
  int n = blockIdx.y, i = blockIdx.x*256 + threadIdx.x;
  float rr = 0.0f, pap = 0.0f;
  if (it == 0) { for (int t = 0; t < 64; ++t) rr += ws[OFF_RR0P + n*64 + t]; }
  else         { for (int t = 0; t < 7;  ++t) rr += ws[OFF_RRP + (it-1)*32 + n*8 + t]; }
  for (int t = 0; t < 64; ++t) pap += ws[OFF_PAPP + it*256 + n*64 + t];
  float alpha = rr / (pap + 1e-30f);
  float rn = 0.0f;
  if (i < MMAT) {
    float dprev = (it == 0) ? 0.0f : ws[OFF_DV + n*MMAT + i];
    float dv = dprev + alpha * ws[OFF_PV + n*MMAT + i];
    rn = ws[OFF_RV + n*MMAT + i] - alpha * ws[OFF_AP + n*MMAT + i];
    ws[OFF_DV + n*MMAT + i] = dv;
    ws[OFF_RV + n*MMAT + i] = rn;
    if (last) out[4194304 + n*MMAT + i] = dv;
  }
  float part = rn*rn;
  WRED(part);
  __shared__ float red[4];
  int lane = threadIdx.x & 63, w = threadIdx.x >> 6;
  if (lane == 0) red[w] = part;
  __syncthreads();
  if (threadIdx.x == 0)
    ws[OFF_RRP + it*32 + n*8 + blockIdx.x] = red[0]+red[1]+red[2]+red[3];
}

// ---------------------------------------------------------------------------
extern "C" void kernel_launch(void* const* d_in, const int* in_sizes, int n_in,
                              void* d_out, int out_size, void* d_ws, size_t ws_size,
                              hipStream_t stream) {
  (void)in_sizes; (void)n_in; (void)out_size; (void)ws_size;
  const float* x    = (const float*)d_in[0];
  const float* dict = (const float*)d_in[1];
  const float* y    = (const float*)d_in[2];
  const float* ax   = (const float*)d_in[3];
  const float* ad   = (const float*)d_in[4];
  const float* regp = (const float*)d_in[5];
  float* out = (float*)d_out;
  float* ws  = (float*)d_ws;   // uses ~47.72 MB (proven budget 47.75 MB)

  dim3 b256(256);
  k_sinv<<<dim3(33,4), b256, 0, stream>>>(dict, ax, ws);
  k_e<<<dim3(64,4), b256, 0, stream>>>(x, dict, y, ws);
  k_fft_rows<<<dim3(33,4), b256, 0, stream>>>(ws);
  k_fft_colpipe<<<dim3(65,4), dim3(128), 0, stream>>>(ws);
  k_ifft_rows<<<dim3(64,4), b256, 0, stream>>>(ws);
  k_xnew<<<dim3(64,4), b256, 0, stream>>>(x, dict, ws, out);

  // ---- R via MFMA: pad->bf16, batched shift-GEMM, slice-merge ----
  k_pad<<<dim3(73,256), b256, 0, stream>>>(out, ws);
  k_gemm<<<dim3(21,8,4), b256, 0, stream>>>(ws);
  k_rmerge<<<dim3(5184), b256, 0, stream>>>(ws);

  k_pm<<<dim3(64,4), b256, 0, stream>>>(out, y, dict, ad, regp, ws);

  // ---- CG solve (R-direct matvec, fused p/Ap recurrence, no atomics) ----
  k_cg_first<<<dim3(64,4), b256, 0, stream>>>(ws, ad, regp);
  for (int it = 0; it < NIT; ++it) {
    k_cg_upd<<<dim3(7,4), b256, 0, stream>>>(ws, it, (it == NIT-1) ? 1 : 0, out);
    if (it < NIT-1)
      k_cg_step<<<dim3(64,4), b256, 0, stream>>>(ws, it, ad, regp);
  }
}